// Round 1
// baseline (7801.614 us; speedup 1.0000x reference)
//
#include <hip/hip_runtime.h>
#include <hip/hip_bf16.h>

// Problem constants (fixed by setup_inputs)
#define BATCH 4
#define NTOK 3137        // 1 + 56*56
#define DIM 768
#define NHEAD 12
#define HD 64
#define QH 56
#define QW 56
#define KH 28
#define KW 28
#define NKEY 785         // 1 + 28*28
#define THREE_DIM 2304
#define MROWS (BATCH*NTOK)   // 12548

// ---------------------------------------------------------------------------
// Tiled fp32 GEMM: C[M][N] = A[M][K] * B[K][N] (+ bias[N]).
// 64x64 tile, BK=16, 256 threads, 4x4 per-thread micro-tile.
// N % 64 == 0, K % 16 == 0 assumed (true for both GEMMs here). M guarded.
// ---------------------------------------------------------------------------
__global__ __launch_bounds__(256) void sgemm64(
    const float* __restrict__ A, const float* __restrict__ B,
    const float* __restrict__ bias, float* __restrict__ C,
    int M, int N, int K)
{
    __shared__ float As[16][64];
    __shared__ float Bs[16][64];
    int t = threadIdx.x;
    int m0 = blockIdx.y * 64;
    int n0 = blockIdx.x * 64;
    int tx = t & 15, ty = t >> 4;

    float acc[4][4] = {};

    int ar = t >> 2;            // A row within tile (0..63)
    int ak = (t & 3) * 4;       // A k offset within tile (0,4,8,12)
    int br = t >> 4;            // B row within tile (0..15)
    int bq = (t & 15) * 4;      // B col offset within tile

    for (int k0 = 0; k0 < K; k0 += 16) {
        float4 av = make_float4(0.f, 0.f, 0.f, 0.f);
        if (m0 + ar < M)
            av = *reinterpret_cast<const float4*>(A + (size_t)(m0 + ar) * K + k0 + ak);
        float4 bv = *reinterpret_cast<const float4*>(B + (size_t)(k0 + br) * N + n0 + bq);
        __syncthreads();
        As[ak + 0][ar] = av.x;
        As[ak + 1][ar] = av.y;
        As[ak + 2][ar] = av.z;
        As[ak + 3][ar] = av.w;
        *reinterpret_cast<float4*>(&Bs[br][bq]) = bv;
        __syncthreads();
        #pragma unroll
        for (int kk = 0; kk < 16; ++kk) {
            float a[4], b[4];
            #pragma unroll
            for (int i = 0; i < 4; ++i) a[i] = As[kk][ty * 4 + i];
            #pragma unroll
            for (int j = 0; j < 4; ++j) b[j] = Bs[kk][tx * 4 + j];
            #pragma unroll
            for (int i = 0; i < 4; ++i)
                #pragma unroll
                for (int j = 0; j < 4; ++j)
                    acc[i][j] += a[i] * b[j];
        }
    }

    #pragma unroll
    for (int i = 0; i < 4; ++i) {
        int m = m0 + ty * 4 + i;
        if (m >= M) break;
        #pragma unroll
        for (int j = 0; j < 4; ++j) {
            int n = n0 + tx * 4 + j;
            float o = acc[i][j];
            if (bias) o += bias[n];
            C[(size_t)m * N + n] = o;
        }
    }
}

// ---------------------------------------------------------------------------
// Depthwise 3x3 pool (+zero pad 1, stride s) + LayerNorm over HEAD_DIM.
// One wave (64 threads) per (b, head, out_pos). qi selects q/k/v slice.
// Output layout: [(b*NHEAD+head) * npos + pos] * 64 + d
// ---------------------------------------------------------------------------
__global__ __launch_bounds__(64) void pool_ln_kernel(
    const float* __restrict__ qkv, const float* __restrict__ w,
    const float* __restrict__ g, const float* __restrict__ beta,
    float* __restrict__ outp, int qi, int stride, int OH, int OW)
{
    int npos = 1 + OH * OW;
    int bid = blockIdx.x;
    int pos = bid % npos;
    int bh  = bid / npos;          // b*NHEAD + head
    int head = bh % NHEAD;
    int b    = bh / NHEAD;
    int d = threadIdx.x;

    const size_t base = (size_t)b * NTOK * THREE_DIM + (size_t)qi * DIM + (size_t)head * HD + d;

    float val;
    if (pos == 0) {
        val = qkv[base];  // cls token, n = 0
    } else {
        int oh = (pos - 1) / OW, ow = (pos - 1) % OW;
        float acc = 0.f;
        #pragma unroll
        for (int r = 0; r < 3; ++r) {
            int ih = oh * stride + r - 1;
            if (ih < 0 || ih >= QH) continue;
            #pragma unroll
            for (int c = 0; c < 3; ++c) {
                int iw = ow * stride + c - 1;
                if (iw < 0 || iw >= QW) continue;
                int n = 1 + ih * QW + iw;
                acc += qkv[base + (size_t)n * THREE_DIM] * w[d * 9 + r * 3 + c];
            }
        }
        val = acc;
    }

    // LayerNorm over 64 lanes (one wave)
    float mu = val;
    #pragma unroll
    for (int off = 32; off > 0; off >>= 1) mu += __shfl_xor(mu, off, 64);
    mu *= (1.f / 64.f);
    float dv = val - mu;
    float var = dv * dv;
    #pragma unroll
    for (int off = 32; off > 0; off >>= 1) var += __shfl_xor(var, off, 64);
    var *= (1.f / 64.f);
    float o = dv * rsqrtf(var + 1e-5f) * g[d] + beta[d];

    outp[((size_t)bh * npos + pos) * HD + d] = o;
}

// ---------------------------------------------------------------------------
// Fused attention: scores (incl. rel-pos bias) + softmax + PV + residual.
// One 256-thread block per (b, head, query row i).
// Writes out[(b*NTOK + i)*768 + head*64 + d]  (B, N, DIM layout for proj GEMM)
// ---------------------------------------------------------------------------
__global__ __launch_bounds__(256) void attn_kernel(
    const float* __restrict__ qp, const float* __restrict__ kp,
    const float* __restrict__ vp,
    const float* __restrict__ rph, const float* __restrict__ rpw,
    float* __restrict__ out)
{
    int bid = blockIdx.x;
    int i  = bid % NTOK;
    int bh = bid / NTOK;           // b*NHEAD + head
    int head = bh % NHEAD;
    int b    = bh / NHEAD;

    const float* qrow  = qp + ((size_t)bh * NTOK + i) * HD;
    const float* kbase = kp + (size_t)bh * NKEY * HD;
    const float* vbase = vp + (size_t)bh * NKEY * HD;

    __shared__ float qs[HD];
    __shared__ float s[NKEY];
    __shared__ float relh[KH];
    __shared__ float relw[KW];
    __shared__ float red[256];
    __shared__ float pv[4][HD];

    int t = threadIdx.x;
    if (t < HD) qs[t] = qrow[t];
    __syncthreads();

    const float scale = 0.125f;   // 64^-0.5

    // raw QK^T scores
    for (int j = t; j < NKEY; j += 256) {
        const float* kr = kbase + (size_t)j * HD;
        float acc = 0.f;
        #pragma unroll
        for (int d = 0; d < HD; d += 4) {
            float4 kv = *reinterpret_cast<const float4*>(kr + d);
            acc += qs[d] * kv.x + qs[d + 1] * kv.y + qs[d + 2] * kv.z + qs[d + 3] * kv.w;
        }
        s[j] = acc * scale;
    }

    // rel-pos dot products (unscaled q)
    if (i > 0) {
        int h = (i - 1) / QW, w = (i - 1) % QW;
        if (t < KH) {
            int idx = h - 2 * t + 54;           // dh(h, kh)
            const float* rr = rph + (size_t)idx * HD;
            float acc = 0.f;
            #pragma unroll
            for (int d = 0; d < HD; ++d) acc += qs[d] * rr[d];
            relh[t] = acc;
        } else if (t >= 32 && t < 32 + KW) {
            int kw = t - 32;
            int idx = w - 2 * kw + 54;          // dw(w, kw)
            const float* rr = rpw + (size_t)idx * HD;
            float acc = 0.f;
            #pragma unroll
            for (int d = 0; d < HD; ++d) acc += qs[d] * rr[d];
            relw[kw] = acc;
        }
    }
    __syncthreads();

    if (i > 0) {
        for (int j = 1 + t; j < NKEY; j += 256) {
            int kh = (j - 1) / KW, kw = (j - 1) % KW;
            s[j] += relh[kh] + relw[kw];
        }
    }
    __syncthreads();

    // softmax: max
    float m = -1e30f;
    for (int j = t; j < NKEY; j += 256) m = fmaxf(m, s[j]);
    red[t] = m;
    __syncthreads();
    for (int off = 128; off > 0; off >>= 1) {
        if (t < off) red[t] = fmaxf(red[t], red[t + off]);
        __syncthreads();
    }
    m = red[0];
    __syncthreads();

    // exp + sum
    float sum = 0.f;
    for (int j = t; j < NKEY; j += 256) {
        float e = __expf(s[j] - m);
        s[j] = e;
        sum += e;
    }
    red[t] = sum;
    __syncthreads();
    for (int off = 128; off > 0; off >>= 1) {
        if (t < off) red[t] += red[t + off];
        __syncthreads();
    }
    float inv = 1.f / red[0];
    __syncthreads();

    // PV: 4 chunks x 64 channels
    int d = t & 63, c = t >> 6;
    float acc = 0.f;
    for (int j = c; j < NKEY; j += 4)
        acc += s[j] * vbase[(size_t)j * HD + d];
    pv[c][d] = acc;
    __syncthreads();

    if (t < HD) {
        float o = (pv[0][t] + pv[1][t] + pv[2][t] + pv[3][t]) * inv;
        if (i > 0) o += qs[t];    // residual (pooled+LN q, unscaled)
        out[((size_t)b * NTOK + i) * DIM + (size_t)head * HD + t] = o;
    }
}

// ---------------------------------------------------------------------------
extern "C" void kernel_launch(void* const* d_in, const int* in_sizes, int n_in,
                              void* d_out, int out_size, void* d_ws, size_t ws_size,
                              hipStream_t stream) {
    const float* x     = (const float*)d_in[0];
    const float* Wqkv  = (const float*)d_in[1];
    const float* pqw   = (const float*)d_in[2];
    const float* pkw   = (const float*)d_in[3];
    const float* pvw   = (const float*)d_in[4];
    const float* gq    = (const float*)d_in[5];
    const float* bq    = (const float*)d_in[6];
    const float* gk    = (const float*)d_in[7];
    const float* bk    = (const float*)d_in[8];
    const float* gv    = (const float*)d_in[9];
    const float* bv    = (const float*)d_in[10];
    const float* rph   = (const float*)d_in[11];
    const float* rpw   = (const float*)d_in[12];
    const float* Wproj = (const float*)d_in[13];
    const float* bproj = (const float*)d_in[14];

    float* ws = (float*)d_ws;
    const size_t qkv_elems = (size_t)MROWS * THREE_DIM;                 // 28,910,592
    const size_t qp_elems  = (size_t)BATCH * NHEAD * NTOK * HD;        //  9,636,864
    const size_t kp_elems  = (size_t)BATCH * NHEAD * NKEY * HD;        //  2,411,520

    float* qkv = ws;
    float* qp  = qkv + qkv_elems;
    float* kp  = qp + qp_elems;
    float* vp  = kp + kp_elems;
    float* attn_out = qkv;   // reuse qkv region (dead after pooling)

    dim3 blk(256);

    // 1) qkv = x @ Wqkv
    {
        dim3 grid(THREE_DIM / 64, (MROWS + 63) / 64);
        sgemm64<<<grid, blk, 0, stream>>>(x, Wqkv, nullptr, qkv, MROWS, THREE_DIM, DIM);
    }

    // 2) pool + LN for q (stride 1), k (stride 2), v (stride 2)
    pool_ln_kernel<<<BATCH * NHEAD * NTOK, 64, 0, stream>>>(qkv, pqw, gq, bq, qp, 0, 1, QH, QW);
    pool_ln_kernel<<<BATCH * NHEAD * NKEY, 64, 0, stream>>>(qkv, pkw, gk, bk, kp, 1, 2, KH, KW);
    pool_ln_kernel<<<BATCH * NHEAD * NKEY, 64, 0, stream>>>(qkv, pvw, gv, bv, vp, 2, 2, KH, KW);

    // 3) fused attention (+rel-pos bias, softmax, PV, residual)
    attn_kernel<<<BATCH * NHEAD * NTOK, 256, 0, stream>>>(qp, kp, vp, rph, rpw, attn_out);

    // 4) out = attn_out @ Wproj + bproj
    {
        dim3 grid(DIM / 64, (MROWS + 63) / 64);
        sgemm64<<<grid, blk, 0, stream>>>(attn_out, Wproj, bproj, (float*)d_out, MROWS, DIM, DIM);
    }
}

// Round 2
// 1295.276 us; speedup vs baseline: 6.0231x; 6.0231x over previous
//
#include <hip/hip_runtime.h>
#include <hip/hip_bf16.h>

// Problem constants (fixed by setup_inputs)
#define BATCH 4
#define NTOK 3137        // 1 + 56*56
#define DIM 768
#define NHEAD 12
#define HD 64
#define QH 56
#define QW 56
#define NKEY 785         // 1 + 28*28
#define NKEYP 792        // padded V^T row length (16B-aligned bf16 rows)
#define THREE_DIM 2304
#define MROWS (BATCH*NTOK)   // 12548
#define QTILE 64
#define NQT 50               // ceil(3137/64)
#define RELC 56              // 28 (kh) + 28 (kw)

typedef __attribute__((ext_vector_type(8))) short bf16x8;
typedef __attribute__((ext_vector_type(4))) float f32x4;

__device__ __forceinline__ unsigned short f2bf(float f) {
    union { float f; unsigned u; } v; v.f = f;
    unsigned r = v.u + 0x7FFFu + ((v.u >> 16) & 1u);   // RNE
    return (unsigned short)(r >> 16);
}
// XOR swizzle for 64B-row LDS tiles (bijective: bits4-6 ^= bits6-8)
__device__ __forceinline__ int swz64(int x) { return x ^ (((x >> 6) & 7) << 4); }

// ---------------------------------------------------------------------------
// Tiled fp32 GEMM: C[M][N] = A[M][K] * B[K][N] (+ bias[N]).  (unchanged)
// ---------------------------------------------------------------------------
__global__ __launch_bounds__(256) void sgemm64(
    const float* __restrict__ A, const float* __restrict__ B,
    const float* __restrict__ bias, float* __restrict__ C,
    int M, int N, int K)
{
    __shared__ float As[16][64];
    __shared__ float Bs[16][64];
    int t = threadIdx.x;
    int m0 = blockIdx.y * 64;
    int n0 = blockIdx.x * 64;
    int tx = t & 15, ty = t >> 4;

    float acc[4][4] = {};

    int ar = t >> 2;
    int ak = (t & 3) * 4;
    int br = t >> 4;
    int bq = (t & 15) * 4;

    for (int k0 = 0; k0 < K; k0 += 16) {
        float4 av = make_float4(0.f, 0.f, 0.f, 0.f);
        if (m0 + ar < M)
            av = *reinterpret_cast<const float4*>(A + (size_t)(m0 + ar) * K + k0 + ak);
        float4 bv = *reinterpret_cast<const float4*>(B + (size_t)(k0 + br) * N + n0 + bq);
        __syncthreads();
        As[ak + 0][ar] = av.x;
        As[ak + 1][ar] = av.y;
        As[ak + 2][ar] = av.z;
        As[ak + 3][ar] = av.w;
        *reinterpret_cast<float4*>(&Bs[br][bq]) = bv;
        __syncthreads();
        #pragma unroll
        for (int kk = 0; kk < 16; ++kk) {
            float a[4], b[4];
            #pragma unroll
            for (int i = 0; i < 4; ++i) a[i] = As[kk][ty * 4 + i];
            #pragma unroll
            for (int j = 0; j < 4; ++j) b[j] = Bs[kk][tx * 4 + j];
            #pragma unroll
            for (int i = 0; i < 4; ++i)
                #pragma unroll
                for (int j = 0; j < 4; ++j)
                    acc[i][j] += a[i] * b[j];
        }
    }

    #pragma unroll
    for (int i = 0; i < 4; ++i) {
        int m = m0 + ty * 4 + i;
        if (m >= M) break;
        #pragma unroll
        for (int j = 0; j < 4; ++j) {
            int n = n0 + tx * 4 + j;
            float o = acc[i][j];
            if (bias) o += bias[n];
            C[(size_t)m * N + n] = o;
        }
    }
}

// ---------------------------------------------------------------------------
// Depthwise 3x3 pool + LayerNorm. mode 0: fp32 [bh][npos][64];
// mode 1: bf16 [bh][npos][64]; mode 2: bf16 transposed [bh][64][ostride]
// ---------------------------------------------------------------------------
__global__ __launch_bounds__(64) void pool_ln_kernel(
    const float* __restrict__ qkv, const float* __restrict__ w,
    const float* __restrict__ g, const float* __restrict__ beta,
    void* __restrict__ outp, int qi, int stride, int OH, int OW,
    int mode, int ostride)
{
    int npos = 1 + OH * OW;
    int bid = blockIdx.x;
    int pos = bid % npos;
    int bh  = bid / npos;
    int head = bh % NHEAD;
    int b    = bh / NHEAD;
    int d = threadIdx.x;

    const size_t base = (size_t)b * NTOK * THREE_DIM + (size_t)qi * DIM + (size_t)head * HD + d;

    float val;
    if (pos == 0) {
        val = qkv[base];
    } else {
        int oh = (pos - 1) / OW, ow = (pos - 1) % OW;
        float acc = 0.f;
        #pragma unroll
        for (int r = 0; r < 3; ++r) {
            int ih = oh * stride + r - 1;
            if (ih < 0 || ih >= QH) continue;
            #pragma unroll
            for (int c = 0; c < 3; ++c) {
                int iw = ow * stride + c - 1;
                if (iw < 0 || iw >= QW) continue;
                int n = 1 + ih * QW + iw;
                acc += qkv[base + (size_t)n * THREE_DIM] * w[d * 9 + r * 3 + c];
            }
        }
        val = acc;
    }

    float mu = val;
    #pragma unroll
    for (int off = 32; off > 0; off >>= 1) mu += __shfl_xor(mu, off, 64);
    mu *= (1.f / 64.f);
    float dv = val - mu;
    float var = dv * dv;
    #pragma unroll
    for (int off = 32; off > 0; off >>= 1) var += __shfl_xor(var, off, 64);
    var *= (1.f / 64.f);
    float o = dv * rsqrtf(var + 1e-5f) * g[d] + beta[d];

    if (mode == 0)
        ((float*)outp)[((size_t)bh * npos + pos) * HD + d] = o;
    else if (mode == 1)
        ((unsigned short*)outp)[((size_t)bh * npos + pos) * HD + d] = f2bf(o);
    else
        ((unsigned short*)outp)[((size_t)bh * HD + d) * ostride + pos] = f2bf(o);
}

// ---------------------------------------------------------------------------
// Rel-pos bias tables: relg[bh][qpos-1][kidx], kidx 0..27 = kh dot, 28..55 = kw dot
// One block per (bh, h-row of query grid).
// ---------------------------------------------------------------------------
__global__ __launch_bounds__(256) void rel_kernel(
    const float* __restrict__ qp, const float* __restrict__ rph,
    const float* __restrict__ rpw, float* __restrict__ relg)
{
    __shared__ float Qs[QH][HD];   // 14 KB
    int blk = blockIdx.x;
    int h = blk % QH;
    int bh = blk / QH;
    int t = threadIdx.x;
    for (int idx = t; idx < QH * HD; idx += 256) {
        int w = idx >> 6, d = idx & 63;
        Qs[w][d] = qp[((size_t)bh * NTOK + 1 + h * QW + w) * HD + d];
    }
    __syncthreads();
    for (int task = t; task < QH * RELC; task += 256) {
        int w = task / RELC, kidx = task % RELC;
        const float* rr;
        if (kidx < 28) rr = rph + (size_t)(h - 2 * kidx + 54) * HD;
        else           rr = rpw + (size_t)(w - 2 * (kidx - 28) + 54) * HD;
        float4 s = make_float4(0.f, 0.f, 0.f, 0.f);
        #pragma unroll
        for (int d = 0; d < HD; d += 4) {
            float4 qv = *reinterpret_cast<const float4*>(&Qs[w][d]);
            float4 rv = *reinterpret_cast<const float4*>(rr + d);
            s.x += qv.x * rv.x; s.y += qv.y * rv.y;
            s.z += qv.z * rv.z; s.w += qv.w * rv.w;
        }
        relg[((size_t)bh * (NTOK - 1) + h * QW + w) * RELC + kidx] = s.x + s.y + s.z + s.w;
    }
}

// ---------------------------------------------------------------------------
// MFMA flash attention. Block = 64 q-rows (4 waves x 16 rows), K-steps of 32.
// No max-subtraction: scores provably bounded (|q|=|k|=8 after LN => |s|<=~10).
// ---------------------------------------------------------------------------
__global__ __launch_bounds__(256) void attn_mfma(
    const float* __restrict__ qp, const unsigned short* __restrict__ kp,
    const unsigned short* __restrict__ vt, const float* __restrict__ relg,
    float* __restrict__ outp)
{
    __shared__ char kbuf[4096];        // K tile  [32][64] bf16, swizzled
    __shared__ char vbuf[4096];        // Vt tile [64][32] bf16, swizzled
    __shared__ char pbuf[4][1024];     // per-wave P [16][32] bf16, swizzled
    __shared__ float rels[QTILE][RELC];

    int bid = blockIdx.x;
    int tile = bid % NQT;
    int bh = bid / NQT;
    int head = bh % NHEAD, b = bh / NHEAD;
    int q0 = tile * QTILE;
    int t = threadIdx.x;
    int wave = t >> 6, lane = t & 63;
    int lm = lane & 15, lkg = lane >> 4;

    const unsigned short* kpb = kp + (size_t)bh * NKEY * HD;
    const unsigned short* vtb = vt + (size_t)bh * HD * NKEYP;

    // rel-bias tile for this block's 64 q-rows
    for (int idx = t; idx < QTILE * RELC; idx += 256) {
        int row = idx / RELC, c = idx % RELC;
        int qpos = q0 + row;
        rels[row][c] = (qpos >= 1 && qpos < NTOK)
            ? relg[((size_t)bh * (NTOK - 1) + qpos - 1) * RELC + c] : 0.f;
    }

    // Q fragments (A-layout: lane holds row lm, k = lkg*8 + i, chunks kc=0,1)
    bf16x8 qfrag[2] = {};
    int qrow = q0 + wave * 16 + lm;
    if (qrow < NTOK) {
        const float* qsrc = qp + ((size_t)bh * NTOK + qrow) * HD + lkg * 8;
        #pragma unroll
        for (int kc = 0; kc < 2; ++kc) {
            float4 a  = *reinterpret_cast<const float4*>(qsrc + kc * 32);
            float4 bb = *reinterpret_cast<const float4*>(qsrc + kc * 32 + 4);
            bf16x8 f;
            f[0] = (short)f2bf(a.x);  f[1] = (short)f2bf(a.y);
            f[2] = (short)f2bf(a.z);  f[3] = (short)f2bf(a.w);
            f[4] = (short)f2bf(bb.x); f[5] = (short)f2bf(bb.y);
            f[6] = (short)f2bf(bb.z); f[7] = (short)f2bf(bb.w);
            qfrag[kc] = f;
        }
    }

    f32x4 oacc[4] = {};            // O accum: 4 d-blocks of 16
    float osum[4] = {0.f, 0.f, 0.f, 0.f};   // per-row softmax denominators

    int krow = t >> 3, kc8 = t & 7;    // K staging role
    int vrow = t >> 2, vc8 = t & 3;    // Vt staging role

    for (int j0 = 0; j0 < NKEY; j0 += 32) {
        __syncthreads();
        // stage K (32 rows x 64 dims bf16)
        {
            int j = j0 + krow;
            int4 val = {0, 0, 0, 0};
            if (j < NKEY)
                val = *reinterpret_cast<const int4*>(kpb + (size_t)j * HD + kc8 * 8);
            *reinterpret_cast<int4*>(&kbuf[krow * 128 + ((kc8 * 16) ^ ((krow & 7) << 4))]) = val;
        }
        // stage Vt (64 d-rows x 32 keys bf16)
        {
            int4 val;
            if (j0 + 31 < NKEY) {
                val = *reinterpret_cast<const int4*>(vtb + (size_t)vrow * NKEYP + j0 + vc8 * 8);
            } else {
                union { int4 v; unsigned short s[8]; } u;
                #pragma unroll
                for (int kk = 0; kk < 8; ++kk) {
                    int jj = j0 + vc8 * 8 + kk;
                    u.s[kk] = (jj < NKEY) ? vtb[(size_t)vrow * NKEYP + jj] : 0;
                }
                val = u.v;
            }
            *reinterpret_cast<int4*>(&vbuf[swz64(vrow * 64 + vc8 * 16)]) = val;
        }
        __syncthreads();

        // QK^T: S[16 q x 32 k] per wave
        f32x4 acc0 = {0.f, 0.f, 0.f, 0.f}, acc1 = {0.f, 0.f, 0.f, 0.f};
        #pragma unroll
        for (int kc = 0; kc < 2; ++kc) {
            bf16x8 kf0 = *reinterpret_cast<const bf16x8*>(
                &kbuf[lm * 128 + ((kc * 64 + lkg * 16) ^ ((lm & 7) << 4))]);
            acc0 = __builtin_amdgcn_mfma_f32_16x16x32_bf16(qfrag[kc], kf0, acc0, 0, 0, 0);
            bf16x8 kf1 = *reinterpret_cast<const bf16x8*>(
                &kbuf[(16 + lm) * 128 + ((kc * 64 + lkg * 16) ^ ((lm & 7) << 4))]);
            acc1 = __builtin_amdgcn_mfma_f32_16x16x32_bf16(qfrag[kc], kf1, acc1, 0, 0, 0);
        }

        // epilogue: scale + rel bias + exp (no max subtraction), pack P to LDS
        #pragma unroll
        for (int nb = 0; nb < 2; ++nb) {
            f32x4 a = nb ? acc1 : acc0;
            int j = j0 + nb * 16 + lm;          // C-layout: col = key = lane&15
            bool valid = j < NKEY;
            bool hasrel = valid && j > 0;
            int kh = 0, kw = 0;
            if (hasrel) { kh = (j - 1) / 28; kw = (j - 1) % 28 + 28; }
            #pragma unroll
            for (int r = 0; r < 4; ++r) {
                float e = 0.f;
                if (valid) {
                    int row = wave * 16 + lkg * 4 + r;   // C-layout row = q
                    float s = a[r] * 0.125f;
                    if (hasrel) s += rels[row][kh] + rels[row][kw];
                    e = __expf(s);
                }
                osum[r] += e;
                int baddr = (lkg * 4 + r) * 64 + (nb * 16 + lm) * 2;
                *reinterpret_cast<unsigned short*>(&pbuf[wave][swz64(baddr)]) = f2bf(e);
            }
        }

        // PV: O += P[16x32] * Vt  (P A-frag read back from LDS, same wave)
        bf16x8 pf = *reinterpret_cast<const bf16x8*>(&pbuf[wave][swz64(lm * 64 + lkg * 16)]);
        #pragma unroll
        for (int db = 0; db < 4; ++db) {
            bf16x8 vf = *reinterpret_cast<const bf16x8*>(
                &vbuf[swz64((db * 16 + lm) * 64 + lkg * 16)]);
            oacc[db] = __builtin_amdgcn_mfma_f32_16x16x32_bf16(pf, vf, oacc[db], 0, 0, 0);
        }
    }

    // finalize: row-sum reduce across the 16 lanes of each row group
    #pragma unroll
    for (int r = 0; r < 4; ++r) {
        float s = osum[r];
        s += __shfl_xor(s, 1, 64);
        s += __shfl_xor(s, 2, 64);
        s += __shfl_xor(s, 4, 64);
        s += __shfl_xor(s, 8, 64);
        osum[r] = 1.f / s;
    }
    #pragma unroll
    for (int r = 0; r < 4; ++r) {
        int qpos = q0 + wave * 16 + lkg * 4 + r;
        if (qpos >= NTOK) continue;
        float* orow = outp + ((size_t)b * NTOK + qpos) * DIM + (size_t)head * HD;
        const float* qres = qp + ((size_t)bh * NTOK + qpos) * HD;
        #pragma unroll
        for (int db = 0; db < 4; ++db) {
            int d = db * 16 + lm;
            float o = oacc[db][r] * osum[r];
            if (qpos > 0) o += qres[d];      // residual (rows 1..)
            orow[d] = o;
        }
    }
}

// ---------------------------------------------------------------------------
extern "C" void kernel_launch(void* const* d_in, const int* in_sizes, int n_in,
                              void* d_out, int out_size, void* d_ws, size_t ws_size,
                              hipStream_t stream) {
    const float* x     = (const float*)d_in[0];
    const float* Wqkv  = (const float*)d_in[1];
    const float* pqw   = (const float*)d_in[2];
    const float* pkw   = (const float*)d_in[3];
    const float* pvw   = (const float*)d_in[4];
    const float* gq    = (const float*)d_in[5];
    const float* bq    = (const float*)d_in[6];
    const float* gk    = (const float*)d_in[7];
    const float* bk    = (const float*)d_in[8];
    const float* gv    = (const float*)d_in[9];
    const float* bv    = (const float*)d_in[10];
    const float* rph   = (const float*)d_in[11];
    const float* rpw   = (const float*)d_in[12];
    const float* Wproj = (const float*)d_in[13];
    const float* bproj = (const float*)d_in[14];

    float* ws = (float*)d_ws;
    const size_t qkv_elems = (size_t)MROWS * THREE_DIM;              // 28,910,592
    const size_t qp_elems  = (size_t)BATCH * NHEAD * NTOK * HD;     //  9,636,864
    const size_t kp_shorts = (size_t)BATCH * NHEAD * NKEY * HD;     //  2,411,520

    float* qkv = ws;
    float* qp  = qkv + qkv_elems;
    unsigned short* kp16 = (unsigned short*)(qp + qp_elems);
    unsigned short* vt16 = kp16 + kp_shorts;     // 4*12*64*792 shorts
    float* relg = qkv + 10000000;                // inside dead qkv region (needs 8,429,568)
    float* attn_out = qkv;                       // first 9,636,864 floats of qkv region

    dim3 blk(256);

    // 1) qkv = x @ Wqkv
    {
        dim3 grid(THREE_DIM / 64, (MROWS + 63) / 64);
        sgemm64<<<grid, blk, 0, stream>>>(x, Wqkv, nullptr, qkv, MROWS, THREE_DIM, DIM);
    }

    // 2) pool + LN: q fp32, k bf16 row-major, v bf16 transposed
    pool_ln_kernel<<<BATCH * NHEAD * NTOK, 64, 0, stream>>>(qkv, pqw, gq, bq, qp,   0, 1, QH, QW, 0, 0);
    pool_ln_kernel<<<BATCH * NHEAD * NKEY, 64, 0, stream>>>(qkv, pkw, gk, bk, kp16, 1, 2, 28, 28, 1, 0);
    pool_ln_kernel<<<BATCH * NHEAD * NKEY, 64, 0, stream>>>(qkv, pvw, gv, bv, vt16, 2, 2, 28, 28, 2, NKEYP);

    // 3) rel-pos bias tables
    rel_kernel<<<BATCH * NHEAD * QH, 256, 0, stream>>>(qp, rph, rpw, relg);

    // 4) MFMA flash attention (+bias, softmax, PV, residual)
    attn_mfma<<<BATCH * NHEAD * NQT, 256, 0, stream>>>(qp, kp16, vt16, relg, attn_out);

    // 5) out = attn_out @ Wproj + bproj
    {
        dim3 grid(DIM / 64, (MROWS + 63) / 64);
        sgemm64<<<grid, blk, 0, stream>>>(attn_out, Wproj, bproj, (float*)d_out, MROWS, DIM, DIM);
    }
}

// Round 3
// 644.339 us; speedup vs baseline: 12.1079x; 2.0102x over previous
//
#include <hip/hip_runtime.h>
#include <hip/hip_bf16.h>

// Problem constants (fixed by setup_inputs)
#define BATCH 4
#define NTOK 3137        // 1 + 56*56
#define DIM 768
#define NHEAD 12
#define HD 64
#define QH 56
#define QW 56
#define NKEY 785         // 1 + 28*28
#define NKEYP 792        // padded V^T row length (16B-aligned bf16 rows)
#define THREE_DIM 2304
#define MROWS (BATCH*NTOK)   // 12548
#define QTILE 64
#define NQT 50               // ceil(3137/64)
#define RELC 56              // 28 (kh) + 28 (kw)

typedef __attribute__((ext_vector_type(8))) short bf16x8;
typedef __attribute__((ext_vector_type(4))) float f32x4;

__device__ __forceinline__ unsigned short f2bf(float f) {
    union { float f; unsigned u; } v; v.f = f;
    unsigned r = v.u + 0x7FFFu + ((v.u >> 16) & 1u);   // RNE
    return (unsigned short)(r >> 16);
}
// XOR swizzle for 64B-row LDS tiles (bijective: bits4-6 ^= bits6-8)
__device__ __forceinline__ int swz64(int x) { return x ^ (((x >> 6) & 7) << 4); }

__device__ __forceinline__ void gl16(const void* g, void* l) {
    __builtin_amdgcn_global_load_lds(
        (const __attribute__((address_space(1))) unsigned int*)g,
        (__attribute__((address_space(3))) unsigned int*)l, 16, 0, 0);
}

// ---------------------------------------------------------------------------
// fp32 -> bf16 elementwise (vectorized x4)
// ---------------------------------------------------------------------------
__global__ __launch_bounds__(256) void cvt_bf16(
    const float* __restrict__ in, unsigned short* __restrict__ outp, int n4)
{
    for (int i = blockIdx.x * 256 + threadIdx.x; i < n4; i += gridDim.x * 256) {
        float4 v = reinterpret_cast<const float4*>(in)[i];
        union { unsigned short s[4]; uint2 u; } o;
        o.s[0] = f2bf(v.x); o.s[1] = f2bf(v.y);
        o.s[2] = f2bf(v.z); o.s[3] = f2bf(v.w);
        reinterpret_cast<uint2*>(outp)[i] = o.u;
    }
}

// ---------------------------------------------------------------------------
// W[K][N] fp32 -> Wt[N][K] bf16 (32x32 LDS tile transpose)
// ---------------------------------------------------------------------------
__global__ __launch_bounds__(256) void transpose_bf16(
    const float* __restrict__ W, unsigned short* __restrict__ Wt, int K, int N)
{
    __shared__ float tile[32][33];
    int k0 = blockIdx.y * 32, n0 = blockIdx.x * 32;
    int t = threadIdx.x;
    int r = t >> 5, c = t & 31;
    #pragma unroll
    for (int p = 0; p < 4; ++p)
        tile[r + p * 8][c] = W[(size_t)(k0 + r + p * 8) * N + n0 + c];
    __syncthreads();
    #pragma unroll
    for (int p = 0; p < 4; ++p)
        Wt[(size_t)(n0 + r + p * 8) * K + k0 + c] = f2bf(tile[c][r + p * 8]);
}

// ---------------------------------------------------------------------------
// bf16 MFMA GEMM: C[M][N] fp32 = A[M][K]bf16 * Bt[N][K]bf16 (+bias).
// 128x128 tile, BK=32, 4 waves (2x2, 64x64 each), global_load_lds staging,
// slot-XOR swizzle sigma(row)=(row>>1)&3 on 16B slots of 64B LDS rows.
// N % 128 == 0, K % 32 == 0 required; M guarded (staging rows clamped).
// ---------------------------------------------------------------------------
__global__ __launch_bounds__(256) void gemm_mfma(
    const unsigned short* __restrict__ A, const unsigned short* __restrict__ Bt,
    const float* __restrict__ bias, float* __restrict__ C,
    int M, int N, int K)
{
    __shared__ __align__(16) char lds[16384];   // A[0..8K), B[8K..16K)
    int t = threadIdx.x;
    int wave = t >> 6, lane = t & 63;
    int lm = lane & 15, lkg = lane >> 4;
    int wr = wave >> 1, wc = wave & 1;
    int m0 = blockIdx.y * 128, n0 = blockIdx.x * 128;

    // staging: linear LDS offsets for this lane's two 16B chunks per matrix
    int o0 = wave * 2048 + lane * 16;
    int o1 = o0 + 1024;
    int r0 = o0 >> 6, s0 = ((o0 >> 4) & 3) ^ ((r0 >> 1) & 3);
    int r1 = o1 >> 6, s1 = ((o1 >> 4) & 3) ^ ((r1 >> 1) & 3);
    int ar0 = m0 + r0; if (ar0 >= M) ar0 = M - 1;
    int ar1 = m0 + r1; if (ar1 >= M) ar1 = M - 1;

    const unsigned short* ap0 = A + (size_t)ar0 * K + s0 * 8;
    const unsigned short* ap1 = A + (size_t)ar1 * K + s1 * 8;
    const unsigned short* bp0 = Bt + (size_t)(n0 + r0) * K + s0 * 8;
    const unsigned short* bp1 = Bt + (size_t)(n0 + r1) * K + s1 * 8;

    char* la0 = &lds[wave * 2048];
    char* la1 = &lds[wave * 2048 + 1024];
    char* lb0 = &lds[8192 + wave * 2048];
    char* lb1 = &lds[8192 + wave * 2048 + 1024];

    f32x4 acc[4][4] = {};

    for (int k0 = 0; k0 < K; k0 += 32) {
        gl16(ap0, la0); gl16(ap1, la1);
        gl16(bp0, lb0); gl16(bp1, lb1);
        ap0 += 32; ap1 += 32; bp0 += 32; bp1 += 32;
        __syncthreads();   // drain staging (vmcnt 0 before barrier)

        bf16x8 af[4], bfr[4];
        #pragma unroll
        for (int m = 0; m < 4; ++m) {
            int row = wr * 64 + m * 16 + lm;
            af[m] = *reinterpret_cast<const bf16x8*>(
                &lds[row * 64 + ((lkg ^ ((row >> 1) & 3)) << 4)]);
        }
        #pragma unroll
        for (int n = 0; n < 4; ++n) {
            int row = wc * 64 + n * 16 + lm;
            bfr[n] = *reinterpret_cast<const bf16x8*>(
                &lds[8192 + row * 64 + ((lkg ^ ((row >> 1) & 3)) << 4)]);
        }
        #pragma unroll
        for (int m = 0; m < 4; ++m)
            #pragma unroll
            for (int n = 0; n < 4; ++n)
                acc[m][n] = __builtin_amdgcn_mfma_f32_16x16x32_bf16(
                    af[m], bfr[n], acc[m][n], 0, 0, 0);
        __syncthreads();   // all waves done reading before next overwrite
    }

    #pragma unroll
    for (int n = 0; n < 4; ++n) {
        int col = n0 + wc * 64 + n * 16 + lm;
        float bval = bias ? bias[col] : 0.f;
        #pragma unroll
        for (int m = 0; m < 4; ++m) {
            int row = m0 + wr * 64 + m * 16 + lkg * 4;
            #pragma unroll
            for (int r = 0; r < 4; ++r) {
                if (row + r < M)
                    C[(size_t)(row + r) * N + col] = acc[m][n][r] + bval;
            }
        }
    }
}

// ---------------------------------------------------------------------------
// Depthwise 3x3 pool + LayerNorm. mode 0: fp32 [bh][npos][64];
// mode 1: bf16 [bh][npos][64]; mode 2: bf16 transposed [bh][64][ostride]
// ---------------------------------------------------------------------------
__global__ __launch_bounds__(64) void pool_ln_kernel(
    const float* __restrict__ qkv, const float* __restrict__ w,
    const float* __restrict__ g, const float* __restrict__ beta,
    void* __restrict__ outp, int qi, int stride, int OH, int OW,
    int mode, int ostride)
{
    int npos = 1 + OH * OW;
    int bid = blockIdx.x;
    int pos = bid % npos;
    int bh  = bid / npos;
    int head = bh % NHEAD;
    int b    = bh / NHEAD;
    int d = threadIdx.x;

    const size_t base = (size_t)b * NTOK * THREE_DIM + (size_t)qi * DIM + (size_t)head * HD + d;

    float val;
    if (pos == 0) {
        val = qkv[base];
    } else {
        int oh = (pos - 1) / OW, ow = (pos - 1) % OW;
        float acc = 0.f;
        #pragma unroll
        for (int r = 0; r < 3; ++r) {
            int ih = oh * stride + r - 1;
            if (ih < 0 || ih >= QH) continue;
            #pragma unroll
            for (int c = 0; c < 3; ++c) {
                int iw = ow * stride + c - 1;
                if (iw < 0 || iw >= QW) continue;
                int n = 1 + ih * QW + iw;
                acc += qkv[base + (size_t)n * THREE_DIM] * w[d * 9 + r * 3 + c];
            }
        }
        val = acc;
    }

    float mu = val;
    #pragma unroll
    for (int off = 32; off > 0; off >>= 1) mu += __shfl_xor(mu, off, 64);
    mu *= (1.f / 64.f);
    float dv = val - mu;
    float var = dv * dv;
    #pragma unroll
    for (int off = 32; off > 0; off >>= 1) var += __shfl_xor(var, off, 64);
    var *= (1.f / 64.f);
    float o = dv * rsqrtf(var + 1e-5f) * g[d] + beta[d];

    if (mode == 0)
        ((float*)outp)[((size_t)bh * npos + pos) * HD + d] = o;
    else if (mode == 1)
        ((unsigned short*)outp)[((size_t)bh * npos + pos) * HD + d] = f2bf(o);
    else
        ((unsigned short*)outp)[((size_t)bh * HD + d) * ostride + pos] = f2bf(o);
}

// ---------------------------------------------------------------------------
// Rel-pos bias tables: relg[bh][qpos-1][kidx], kidx 0..27 = kh dot, 28..55 = kw
// ---------------------------------------------------------------------------
__global__ __launch_bounds__(256) void rel_kernel(
    const float* __restrict__ qp, const float* __restrict__ rph,
    const float* __restrict__ rpw, float* __restrict__ relg)
{
    __shared__ float Qs[QH][HD];   // 14 KB
    int blk = blockIdx.x;
    int h = blk % QH;
    int bh = blk / QH;
    int t = threadIdx.x;
    for (int idx = t; idx < QH * HD; idx += 256) {
        int w = idx >> 6, d = idx & 63;
        Qs[w][d] = qp[((size_t)bh * NTOK + 1 + h * QW + w) * HD + d];
    }
    __syncthreads();
    for (int task = t; task < QH * RELC; task += 256) {
        int w = task / RELC, kidx = task % RELC;
        const float* rr;
        if (kidx < 28) rr = rph + (size_t)(h - 2 * kidx + 54) * HD;
        else           rr = rpw + (size_t)(w - 2 * (kidx - 28) + 54) * HD;
        float4 s = make_float4(0.f, 0.f, 0.f, 0.f);
        #pragma unroll
        for (int d = 0; d < HD; d += 4) {
            float4 qv = *reinterpret_cast<const float4*>(&Qs[w][d]);
            float4 rv = *reinterpret_cast<const float4*>(rr + d);
            s.x += qv.x * rv.x; s.y += qv.y * rv.y;
            s.z += qv.z * rv.z; s.w += qv.w * rv.w;
        }
        relg[((size_t)bh * (NTOK - 1) + h * QW + w) * RELC + kidx] = s.x + s.y + s.z + s.w;
    }
}

// ---------------------------------------------------------------------------
// MFMA flash attention. Block = 64 q-rows (4 waves x 16 rows), K-steps of 32.
// No max-subtraction: scores provably bounded (|q|=|k|=8 after LN => |s|<=~10).
// Output written directly as bf16 (A-operand of the proj GEMM).
// ---------------------------------------------------------------------------
__global__ __launch_bounds__(256) void attn_mfma(
    const float* __restrict__ qp, const unsigned short* __restrict__ kp,
    const unsigned short* __restrict__ vt, const float* __restrict__ relg,
    unsigned short* __restrict__ outp)
{
    __shared__ char kbuf[4096];        // K tile  [32][64] bf16, swizzled
    __shared__ char vbuf[4096];        // Vt tile [64][32] bf16, swizzled
    __shared__ char pbuf[4][1024];     // per-wave P [16][32] bf16, swizzled
    __shared__ float rels[QTILE][RELC];

    int bid = blockIdx.x;
    int tile = bid % NQT;
    int bh = bid / NQT;
    int head = bh % NHEAD, b = bh / NHEAD;
    int q0 = tile * QTILE;
    int t = threadIdx.x;
    int wave = t >> 6, lane = t & 63;
    int lm = lane & 15, lkg = lane >> 4;

    const unsigned short* kpb = kp + (size_t)bh * NKEY * HD;
    const unsigned short* vtb = vt + (size_t)bh * HD * NKEYP;

    for (int idx = t; idx < QTILE * RELC; idx += 256) {
        int row = idx / RELC, c = idx % RELC;
        int qpos = q0 + row;
        rels[row][c] = (qpos >= 1 && qpos < NTOK)
            ? relg[((size_t)bh * (NTOK - 1) + qpos - 1) * RELC + c] : 0.f;
    }

    bf16x8 qfrag[2] = {};
    int qrow = q0 + wave * 16 + lm;
    if (qrow < NTOK) {
        const float* qsrc = qp + ((size_t)bh * NTOK + qrow) * HD + lkg * 8;
        #pragma unroll
        for (int kc = 0; kc < 2; ++kc) {
            float4 a  = *reinterpret_cast<const float4*>(qsrc + kc * 32);
            float4 bb = *reinterpret_cast<const float4*>(qsrc + kc * 32 + 4);
            bf16x8 f;
            f[0] = (short)f2bf(a.x);  f[1] = (short)f2bf(a.y);
            f[2] = (short)f2bf(a.z);  f[3] = (short)f2bf(a.w);
            f[4] = (short)f2bf(bb.x); f[5] = (short)f2bf(bb.y);
            f[6] = (short)f2bf(bb.z); f[7] = (short)f2bf(bb.w);
            qfrag[kc] = f;
        }
    }

    f32x4 oacc[4] = {};
    float osum[4] = {0.f, 0.f, 0.f, 0.f};

    int krow = t >> 3, kc8 = t & 7;
    int vrow = t >> 2, vc8 = t & 3;

    for (int j0 = 0; j0 < NKEY; j0 += 32) {
        __syncthreads();
        {
            int j = j0 + krow;
            int4 val = {0, 0, 0, 0};
            if (j < NKEY)
                val = *reinterpret_cast<const int4*>(kpb + (size_t)j * HD + kc8 * 8);
            *reinterpret_cast<int4*>(&kbuf[krow * 128 + ((kc8 * 16) ^ ((krow & 7) << 4))]) = val;
        }
        {
            int4 val;
            if (j0 + 31 < NKEY) {
                val = *reinterpret_cast<const int4*>(vtb + (size_t)vrow * NKEYP + j0 + vc8 * 8);
            } else {
                union { int4 v; unsigned short s[8]; } u;
                #pragma unroll
                for (int kk = 0; kk < 8; ++kk) {
                    int jj = j0 + vc8 * 8 + kk;
                    u.s[kk] = (jj < NKEY) ? vtb[(size_t)vrow * NKEYP + jj] : 0;
                }
                val = u.v;
            }
            *reinterpret_cast<int4*>(&vbuf[swz64(vrow * 64 + vc8 * 16)]) = val;
        }
        __syncthreads();

        f32x4 acc0 = {0.f, 0.f, 0.f, 0.f}, acc1 = {0.f, 0.f, 0.f, 0.f};
        #pragma unroll
        for (int kc = 0; kc < 2; ++kc) {
            bf16x8 kf0 = *reinterpret_cast<const bf16x8*>(
                &kbuf[lm * 128 + ((kc * 64 + lkg * 16) ^ ((lm & 7) << 4))]);
            acc0 = __builtin_amdgcn_mfma_f32_16x16x32_bf16(qfrag[kc], kf0, acc0, 0, 0, 0);
            bf16x8 kf1 = *reinterpret_cast<const bf16x8*>(
                &kbuf[(16 + lm) * 128 + ((kc * 64 + lkg * 16) ^ ((lm & 7) << 4))]);
            acc1 = __builtin_amdgcn_mfma_f32_16x16x32_bf16(qfrag[kc], kf1, acc1, 0, 0, 0);
        }

        #pragma unroll
        for (int nb = 0; nb < 2; ++nb) {
            f32x4 a = nb ? acc1 : acc0;
            int j = j0 + nb * 16 + lm;
            bool valid = j < NKEY;
            bool hasrel = valid && j > 0;
            int kh = 0, kw = 0;
            if (hasrel) { kh = (j - 1) / 28; kw = (j - 1) % 28 + 28; }
            #pragma unroll
            for (int r = 0; r < 4; ++r) {
                float e = 0.f;
                if (valid) {
                    int row = wave * 16 + lkg * 4 + r;
                    float s = a[r] * 0.125f;
                    if (hasrel) s += rels[row][kh] + rels[row][kw];
                    e = __expf(s);
                }
                osum[r] += e;
                int baddr = (lkg * 4 + r) * 64 + (nb * 16 + lm) * 2;
                *reinterpret_cast<unsigned short*>(&pbuf[wave][swz64(baddr)]) = f2bf(e);
            }
        }

        bf16x8 pf = *reinterpret_cast<const bf16x8*>(&pbuf[wave][swz64(lm * 64 + lkg * 16)]);
        #pragma unroll
        for (int db = 0; db < 4; ++db) {
            bf16x8 vf = *reinterpret_cast<const bf16x8*>(
                &vbuf[swz64((db * 16 + lm) * 64 + lkg * 16)]);
            oacc[db] = __builtin_amdgcn_mfma_f32_16x16x32_bf16(pf, vf, oacc[db], 0, 0, 0);
        }
    }

    #pragma unroll
    for (int r = 0; r < 4; ++r) {
        float s = osum[r];
        s += __shfl_xor(s, 1, 64);
        s += __shfl_xor(s, 2, 64);
        s += __shfl_xor(s, 4, 64);
        s += __shfl_xor(s, 8, 64);
        osum[r] = 1.f / s;
    }
    #pragma unroll
    for (int r = 0; r < 4; ++r) {
        int qpos = q0 + wave * 16 + lkg * 4 + r;
        if (qpos >= NTOK) continue;
        unsigned short* orow = outp + ((size_t)b * NTOK + qpos) * DIM + (size_t)head * HD;
        const float* qres = qp + ((size_t)bh * NTOK + qpos) * HD;
        #pragma unroll
        for (int db = 0; db < 4; ++db) {
            int d = db * 16 + lm;
            float o = oacc[db][r] * osum[r];
            if (qpos > 0) o += qres[d];
            orow[d] = f2bf(o);
        }
    }
}

// ---------------------------------------------------------------------------
extern "C" void kernel_launch(void* const* d_in, const int* in_sizes, int n_in,
                              void* d_out, int out_size, void* d_ws, size_t ws_size,
                              hipStream_t stream) {
    const float* x     = (const float*)d_in[0];
    const float* Wqkv  = (const float*)d_in[1];
    const float* pqw   = (const float*)d_in[2];
    const float* pkw   = (const float*)d_in[3];
    const float* pvw   = (const float*)d_in[4];
    const float* gq    = (const float*)d_in[5];
    const float* bq    = (const float*)d_in[6];
    const float* gk    = (const float*)d_in[7];
    const float* bk    = (const float*)d_in[8];
    const float* gv    = (const float*)d_in[9];
    const float* bv    = (const float*)d_in[10];
    const float* rph   = (const float*)d_in[11];
    const float* rpw   = (const float*)d_in[12];
    const float* Wproj = (const float*)d_in[13];
    const float* bproj = (const float*)d_in[14];

    float* ws = (float*)d_ws;
    const size_t qkv_elems = (size_t)MROWS * THREE_DIM;              // 28,910,592
    const size_t qp_elems  = (size_t)BATCH * NHEAD * NTOK * HD;     //  9,636,864
    const size_t kp_shorts = (size_t)BATCH * NHEAD * NKEY * HD;     //  2,411,520
    const size_t vt_shorts = (size_t)BATCH * NHEAD * HD * NKEYP;    //  2,433,024

    float* qkv = ws;                                   // fp32, dead after pools
    float* qp  = qkv + qkv_elems;
    unsigned short* kp16 = (unsigned short*)(qp + qp_elems);
    unsigned short* vt16 = kp16 + kp_shorts;
    unsigned short* xbf  = (unsigned short*)(vt16 + vt_shorts);          // [M][768] bf16
    unsigned short* wqkvt = xbf + qp_elems;                              // [2304][768] bf16
    // carved out of the dead qkv region:
    unsigned short* attn_bf = (unsigned short*)qkv;    // [M][768] bf16 (4.82M floats)
    float* relg = qkv + 10000000;                      // 8,429,568 floats
    unsigned short* wprojt = (unsigned short*)(qkv + 20000000);          // [768][768] bf16

    dim3 blk(256);

    // 0) bf16 conversions for GEMM1 operands
    cvt_bf16<<<2048, blk, 0, stream>>>(x, xbf, (int)((size_t)MROWS * DIM / 4));
    {
        dim3 g(THREE_DIM / 32, DIM / 32);
        transpose_bf16<<<g, blk, 0, stream>>>(Wqkv, wqkvt, DIM, THREE_DIM);
    }

    // 1) qkv = x @ Wqkv   (bf16 MFMA, fp32 out)
    {
        dim3 grid(THREE_DIM / 128, (MROWS + 127) / 128);
        gemm_mfma<<<grid, blk, 0, stream>>>(xbf, wqkvt, nullptr, qkv, MROWS, THREE_DIM, DIM);
    }

    // 2) pool + LN: q fp32, k bf16 row-major, v bf16 transposed
    pool_ln_kernel<<<BATCH * NHEAD * NTOK, 64, 0, stream>>>(qkv, pqw, gq, bq, qp,   0, 1, QH, QW, 0, 0);
    pool_ln_kernel<<<BATCH * NHEAD * NKEY, 64, 0, stream>>>(qkv, pkw, gk, bk, kp16, 1, 2, 28, 28, 1, 0);
    pool_ln_kernel<<<BATCH * NHEAD * NKEY, 64, 0, stream>>>(qkv, pvw, gv, bv, vt16, 2, 2, 28, 28, 2, NKEYP);

    // 3) rel-pos bias tables + proj weight transpose (qkv region now dead)
    rel_kernel<<<BATCH * NHEAD * QH, blk, 0, stream>>>(qp, rph, rpw, relg);
    {
        dim3 g(DIM / 32, DIM / 32);
        transpose_bf16<<<g, blk, 0, stream>>>(Wproj, wprojt, DIM, DIM);
    }

    // 4) MFMA flash attention (+bias, softmax, PV, residual) -> bf16
    attn_mfma<<<BATCH * NHEAD * NQT, blk, 0, stream>>>(qp, kp16, vt16, relg, attn_bf);

    // 5) out = attn_out @ Wproj + bproj   (bf16 MFMA, fp32 out)
    {
        dim3 grid(DIM / 128, (MROWS + 127) / 128);
        gemm_mfma<<<grid, blk, 0, stream>>>(attn_bf, wprojt, bproj, (float*)d_out, MROWS, DIM, DIM);
    }
}

// Round 4
// 417.701 us; speedup vs baseline: 18.6775x; 1.5426x over previous
//
#include <hip/hip_runtime.h>
#include <hip/hip_bf16.h>

// Problem constants (fixed by setup_inputs)
#define BATCH 4
#define NTOK 3137        // 1 + 56*56
#define DIM 768
#define NHEAD 12
#define HD 64
#define QH 56
#define QW 56
#define NKEY 785         // 1 + 28*28
#define NKEYP 792        // padded V^T row length (16B-aligned bf16 rows)
#define THREE_DIM 2304
#define MROWS (BATCH*NTOK)   // 12548
#define QTILE 64
#define NQT 50               // ceil(3137/64)
#define RELC 56              // 28 (kh) + 28 (kw)
#define NBH 48               // BATCH*NHEAD
#define RELROWS (NBH*56)     // 2688

typedef __attribute__((ext_vector_type(8))) short bf16x8;
typedef __attribute__((ext_vector_type(4))) float f32x4;

__device__ __forceinline__ unsigned short f2bf(float f) {
    union { float f; unsigned u; } v; v.f = f;
    unsigned r = v.u + 0x7FFFu + ((v.u >> 16) & 1u);   // RNE
    return (unsigned short)(r >> 16);
}
__device__ __forceinline__ float bf2f(unsigned short s) {
    union { unsigned u; float f; } v; v.u = (unsigned)s << 16; return v.f;
}
// XOR swizzle for 64B-row LDS tiles (bijective: bits4-6 ^= bits6-8)
__device__ __forceinline__ int swz64(int x) { return x ^ (((x >> 6) & 7) << 4); }

__device__ __forceinline__ void gl16(const void* g, void* l) {
    __builtin_amdgcn_global_load_lds(
        (const __attribute__((address_space(1))) unsigned int*)g,
        (__attribute__((address_space(3))) unsigned int*)l, 16, 0, 0);
}

// ---------------------------------------------------------------------------
// fp32 -> bf16 elementwise (vectorized x4)
// ---------------------------------------------------------------------------
__global__ __launch_bounds__(256) void cvt_bf16(
    const float* __restrict__ in, unsigned short* __restrict__ outp, int n4)
{
    for (int i = blockIdx.x * 256 + threadIdx.x; i < n4; i += gridDim.x * 256) {
        float4 v = reinterpret_cast<const float4*>(in)[i];
        union { unsigned short s[4]; uint2 u; } o;
        o.s[0] = f2bf(v.x); o.s[1] = f2bf(v.y);
        o.s[2] = f2bf(v.z); o.s[3] = f2bf(v.w);
        reinterpret_cast<uint2*>(outp)[i] = o.u;
    }
}

// ---------------------------------------------------------------------------
// W[K][N] fp32 -> Wt[N][K] bf16 (32x32 LDS tile transpose)
// ---------------------------------------------------------------------------
__global__ __launch_bounds__(256) void transpose_bf16(
    const float* __restrict__ W, unsigned short* __restrict__ Wt, int K, int N)
{
    __shared__ float tile[32][33];
    int k0 = blockIdx.y * 32, n0 = blockIdx.x * 32;
    int t = threadIdx.x;
    int r = t >> 5, c = t & 31;
    #pragma unroll
    for (int p = 0; p < 4; ++p)
        tile[r + p * 8][c] = W[(size_t)(k0 + r + p * 8) * N + n0 + c];
    __syncthreads();
    #pragma unroll
    for (int p = 0; p < 4; ++p)
        Wt[(size_t)(n0 + r + p * 8) * K + k0 + c] = f2bf(tile[c][r + p * 8]);
}

// ---------------------------------------------------------------------------
// bf16 MFMA GEMM: C[M][N] fp32 = A[M][K]bf16 * Bt[N][K]bf16 (+bias).
// 128x128 tile, BK=32, 4 waves (2x2, 64x64 each), global_load_lds staging.
// ---------------------------------------------------------------------------
__global__ __launch_bounds__(256) void gemm_mfma(
    const unsigned short* __restrict__ A, const unsigned short* __restrict__ Bt,
    const float* __restrict__ bias, float* __restrict__ C,
    int M, int N, int K)
{
    __shared__ __align__(16) char lds[16384];   // A[0..8K), B[8K..16K)
    int t = threadIdx.x;
    int wave = t >> 6, lane = t & 63;
    int lm = lane & 15, lkg = lane >> 4;
    int wr = wave >> 1, wc = wave & 1;
    int m0 = blockIdx.y * 128, n0 = blockIdx.x * 128;

    int o0 = wave * 2048 + lane * 16;
    int o1 = o0 + 1024;
    int r0 = o0 >> 6, s0 = ((o0 >> 4) & 3) ^ ((r0 >> 1) & 3);
    int r1 = o1 >> 6, s1 = ((o1 >> 4) & 3) ^ ((r1 >> 1) & 3);
    int ar0 = m0 + r0; if (ar0 >= M) ar0 = M - 1;
    int ar1 = m0 + r1; if (ar1 >= M) ar1 = M - 1;

    const unsigned short* ap0 = A + (size_t)ar0 * K + s0 * 8;
    const unsigned short* ap1 = A + (size_t)ar1 * K + s1 * 8;
    const unsigned short* bp0 = Bt + (size_t)(n0 + r0) * K + s0 * 8;
    const unsigned short* bp1 = Bt + (size_t)(n0 + r1) * K + s1 * 8;

    char* la0 = &lds[wave * 2048];
    char* la1 = &lds[wave * 2048 + 1024];
    char* lb0 = &lds[8192 + wave * 2048];
    char* lb1 = &lds[8192 + wave * 2048 + 1024];

    f32x4 acc[4][4] = {};

    for (int k0 = 0; k0 < K; k0 += 32) {
        gl16(ap0, la0); gl16(ap1, la1);
        gl16(bp0, lb0); gl16(bp1, lb1);
        ap0 += 32; ap1 += 32; bp0 += 32; bp1 += 32;
        __syncthreads();

        bf16x8 af[4], bfr[4];
        #pragma unroll
        for (int m = 0; m < 4; ++m) {
            int row = wr * 64 + m * 16 + lm;
            af[m] = *reinterpret_cast<const bf16x8*>(
                &lds[row * 64 + ((lkg ^ ((row >> 1) & 3)) << 4)]);
        }
        #pragma unroll
        for (int n = 0; n < 4; ++n) {
            int row = wc * 64 + n * 16 + lm;
            bfr[n] = *reinterpret_cast<const bf16x8*>(
                &lds[8192 + row * 64 + ((lkg ^ ((row >> 1) & 3)) << 4)]);
        }
        #pragma unroll
        for (int m = 0; m < 4; ++m)
            #pragma unroll
            for (int n = 0; n < 4; ++n)
                acc[m][n] = __builtin_amdgcn_mfma_f32_16x16x32_bf16(
                    af[m], bfr[n], acc[m][n], 0, 0, 0);
        __syncthreads();
    }

    #pragma unroll
    for (int n = 0; n < 4; ++n) {
        int col = n0 + wc * 64 + n * 16 + lm;
        float bval = bias ? bias[col] : 0.f;
        #pragma unroll
        for (int m = 0; m < 4; ++m) {
            int row = m0 + wr * 64 + m * 16 + lkg * 4;
            #pragma unroll
            for (int r = 0; r < 4; ++r) {
                if (row + r < M)
                    C[(size_t)(row + r) * N + col] = acc[m][n][r] + bval;
            }
        }
    }
}

// ---------------------------------------------------------------------------
// Depthwise 3x3 pool + LayerNorm.
// mode 1: bf16 [bh][npos][64]; mode 2: bf16 transposed [bh][64][ostride]
// ---------------------------------------------------------------------------
__global__ __launch_bounds__(64) void pool_ln_kernel(
    const float* __restrict__ qkv, const float* __restrict__ w,
    const float* __restrict__ g, const float* __restrict__ beta,
    void* __restrict__ outp, int qi, int stride, int OH, int OW,
    int mode, int ostride)
{
    int npos = 1 + OH * OW;
    int bid = blockIdx.x;
    int pos = bid % npos;
    int bh  = bid / npos;
    int head = bh % NHEAD;
    int b    = bh / NHEAD;
    int d = threadIdx.x;

    const size_t base = (size_t)b * NTOK * THREE_DIM + (size_t)qi * DIM + (size_t)head * HD + d;

    float val;
    if (pos == 0) {
        val = qkv[base];
    } else {
        int oh = (pos - 1) / OW, ow = (pos - 1) % OW;
        float acc = 0.f;
        #pragma unroll
        for (int r = 0; r < 3; ++r) {
            int ih = oh * stride + r - 1;
            if (ih < 0 || ih >= QH) continue;
            #pragma unroll
            for (int c = 0; c < 3; ++c) {
                int iw = ow * stride + c - 1;
                if (iw < 0 || iw >= QW) continue;
                int n = 1 + ih * QW + iw;
                acc += qkv[base + (size_t)n * THREE_DIM] * w[d * 9 + r * 3 + c];
            }
        }
        val = acc;
    }

    float mu = val;
    #pragma unroll
    for (int off = 32; off > 0; off >>= 1) mu += __shfl_xor(mu, off, 64);
    mu *= (1.f / 64.f);
    float dv = val - mu;
    float var = dv * dv;
    #pragma unroll
    for (int off = 32; off > 0; off >>= 1) var += __shfl_xor(var, off, 64);
    var *= (1.f / 64.f);
    float o = dv * rsqrtf(var + 1e-5f) * g[d] + beta[d];

    if (mode == 1)
        ((unsigned short*)outp)[((size_t)bh * npos + pos) * HD + d] = f2bf(o);
    else
        ((unsigned short*)outp)[((size_t)bh * HD + d) * ostride + pos] = f2bf(o);
}

// ---------------------------------------------------------------------------
// MFMA rel-pos bias: for fixed X (=h or =w), GEMM [2688 rows x 64] @ [64 x 28].
// mode 0 (rel_h): rows=(bh,w), table row X-2k+54 of rphb; kidx 0..27
// mode 1 (rel_w): rows=(bh,h), table row X-2k+54 of rpwb; kidx 28..55
// Block: 4 waves x 64 rows = 256 rows. Grid (56, 11).
// ---------------------------------------------------------------------------
__global__ __launch_bounds__(256) void rel_mfma(
    const unsigned short* __restrict__ qpb, const unsigned short* __restrict__ rtab,
    float* __restrict__ relg, int mode)
{
    __shared__ char bbuf[4096];     // [32 rows][64 bf16], XOR-swizzled
    int X = blockIdx.x;
    int m0 = blockIdx.y * 256;
    int t = threadIdx.x;
    int wave = t >> 6, lane = t & 63;
    int lm = lane & 15, lkg = lane >> 4;

    // stage B (rows >= 28 zeroed)
    {
        int row = t >> 3, c8 = t & 7;
        int4 val = {0, 0, 0, 0};
        if (row < 28) {
            int dh = X - 2 * row + 54;              // in [0, 110)
            val = *reinterpret_cast<const int4*>(rtab + (size_t)dh * HD + c8 * 8);
        }
        *reinterpret_cast<int4*>(&bbuf[row * 128 + ((c8 * 16) ^ ((row & 7) << 4))]) = val;
    }
    __syncthreads();

    int rbase = m0 + wave * 64 + lm;
    f32x4 acc[4][2] = {};
    #pragma unroll
    for (int kc = 0; kc < 2; ++kc) {
        bf16x8 bfrag[2];
        #pragma unroll
        for (int nb = 0; nb < 2; ++nb) {
            int row = nb * 16 + lm;
            bfrag[nb] = *reinterpret_cast<const bf16x8*>(
                &bbuf[row * 128 + (((kc * 4 + lkg) * 16) ^ ((row & 7) << 4))]);
        }
        #pragma unroll
        for (int m = 0; m < 4; ++m) {
            int rho = rbase + m * 16; if (rho > RELROWS - 1) rho = RELROWS - 1;
            int bh = rho / 56, rem = rho % 56;
            int pos1 = (mode == 0) ? X * 56 + rem : rem * 56 + X;
            const unsigned short* qsrc =
                qpb + ((size_t)bh * NTOK + 1 + pos1) * HD + kc * 32 + lkg * 8;
            bf16x8 af = *reinterpret_cast<const bf16x8*>(qsrc);
            acc[m][0] = __builtin_amdgcn_mfma_f32_16x16x32_bf16(af, bfrag[0], acc[m][0], 0, 0, 0);
            acc[m][1] = __builtin_amdgcn_mfma_f32_16x16x32_bf16(af, bfrag[1], acc[m][1], 0, 0, 0);
        }
    }

    #pragma unroll
    for (int m = 0; m < 4; ++m) {
        #pragma unroll
        for (int r = 0; r < 4; ++r) {
            int rho = m0 + wave * 64 + m * 16 + lkg * 4 + r;
            if (rho >= RELROWS) continue;
            int bh = rho / 56, rem = rho % 56;
            int pos1 = (mode == 0) ? X * 56 + rem : rem * 56 + X;
            float* dst = relg + ((size_t)bh * (NTOK - 1) + pos1) * RELC + mode * 28;
            dst[lm] = acc[m][0][r];                 // cols 0..15
            if (lm < 12) dst[16 + lm] = acc[m][1][r];   // cols 16..27
        }
    }
}

// ---------------------------------------------------------------------------
// MFMA flash attention. Block = 64 q-rows (4 waves x 16 rows), K-steps of 32.
// No max-subtraction: scores provably bounded (|q|=|k|=8 after LN => |s|<=~10).
// Output written directly as bf16 (A-operand of the proj GEMM).
// ---------------------------------------------------------------------------
__global__ __launch_bounds__(256) void attn_mfma(
    const unsigned short* __restrict__ qpb, const unsigned short* __restrict__ kp,
    const unsigned short* __restrict__ vt, const float* __restrict__ relg,
    unsigned short* __restrict__ outp)
{
    __shared__ char kbuf[4096];        // K tile  [32][64] bf16, swizzled
    __shared__ char vbuf[4096];        // Vt tile [64][32] bf16, swizzled
    __shared__ char pbuf[4][1024];     // per-wave P [16][32] bf16, swizzled
    __shared__ float rels[QTILE][RELC];

    int bid = blockIdx.x;
    int tile = bid % NQT;
    int bh = bid / NQT;
    int head = bh % NHEAD, b = bh / NHEAD;
    int q0 = tile * QTILE;
    int t = threadIdx.x;
    int wave = t >> 6, lane = t & 63;
    int lm = lane & 15, lkg = lane >> 4;

    const unsigned short* kpb = kp + (size_t)bh * NKEY * HD;
    const unsigned short* vtb = vt + (size_t)bh * HD * NKEYP;

    for (int idx = t; idx < QTILE * RELC; idx += 256) {
        int row = idx / RELC, c = idx % RELC;
        int qpos = q0 + row;
        rels[row][c] = (qpos >= 1 && qpos < NTOK)
            ? relg[((size_t)bh * (NTOK - 1) + qpos - 1) * RELC + c] : 0.f;
    }

    bf16x8 qfrag[2] = {};
    int qrow = q0 + wave * 16 + lm;
    if (qrow < NTOK) {
        const unsigned short* qsrc = qpb + ((size_t)bh * NTOK + qrow) * HD + lkg * 8;
        qfrag[0] = *reinterpret_cast<const bf16x8*>(qsrc);
        qfrag[1] = *reinterpret_cast<const bf16x8*>(qsrc + 32);
    }

    f32x4 oacc[4] = {};
    float osum[4] = {0.f, 0.f, 0.f, 0.f};

    int krow = t >> 3, kc8 = t & 7;
    int vrow = t >> 2, vc8 = t & 3;

    for (int j0 = 0; j0 < NKEY; j0 += 32) {
        __syncthreads();
        {
            int j = j0 + krow;
            int4 val = {0, 0, 0, 0};
            if (j < NKEY)
                val = *reinterpret_cast<const int4*>(kpb + (size_t)j * HD + kc8 * 8);
            *reinterpret_cast<int4*>(&kbuf[krow * 128 + ((kc8 * 16) ^ ((krow & 7) << 4))]) = val;
        }
        {
            int4 val;
            if (j0 + 31 < NKEY) {
                val = *reinterpret_cast<const int4*>(vtb + (size_t)vrow * NKEYP + j0 + vc8 * 8);
            } else {
                union { int4 v; unsigned short s[8]; } u;
                #pragma unroll
                for (int kk = 0; kk < 8; ++kk) {
                    int jj = j0 + vc8 * 8 + kk;
                    u.s[kk] = (jj < NKEY) ? vtb[(size_t)vrow * NKEYP + jj] : 0;
                }
                val = u.v;
            }
            *reinterpret_cast<int4*>(&vbuf[swz64(vrow * 64 + vc8 * 16)]) = val;
        }
        __syncthreads();

        f32x4 acc0 = {0.f, 0.f, 0.f, 0.f}, acc1 = {0.f, 0.f, 0.f, 0.f};
        #pragma unroll
        for (int kc = 0; kc < 2; ++kc) {
            bf16x8 kf0 = *reinterpret_cast<const bf16x8*>(
                &kbuf[lm * 128 + ((kc * 64 + lkg * 16) ^ ((lm & 7) << 4))]);
            acc0 = __builtin_amdgcn_mfma_f32_16x16x32_bf16(qfrag[kc], kf0, acc0, 0, 0, 0);
            bf16x8 kf1 = *reinterpret_cast<const bf16x8*>(
                &kbuf[(16 + lm) * 128 + ((kc * 64 + lkg * 16) ^ ((lm & 7) << 4))]);
            acc1 = __builtin_amdgcn_mfma_f32_16x16x32_bf16(qfrag[kc], kf1, acc1, 0, 0, 0);
        }

        #pragma unroll
        for (int nb = 0; nb < 2; ++nb) {
            f32x4 a = nb ? acc1 : acc0;
            int j = j0 + nb * 16 + lm;
            bool valid = j < NKEY;
            bool hasrel = valid && j > 0;
            int kh = 0, kw = 0;
            if (hasrel) { kh = (j - 1) / 28; kw = (j - 1) % 28 + 28; }
            #pragma unroll
            for (int r = 0; r < 4; ++r) {
                float e = 0.f;
                if (valid) {
                    int row = wave * 16 + lkg * 4 + r;
                    float s = a[r] * 0.125f;
                    if (hasrel) s += rels[row][kh] + rels[row][kw];
                    e = __expf(s);
                }
                osum[r] += e;
                int baddr = (lkg * 4 + r) * 64 + (nb * 16 + lm) * 2;
                *reinterpret_cast<unsigned short*>(&pbuf[wave][swz64(baddr)]) = f2bf(e);
            }
        }

        bf16x8 pf = *reinterpret_cast<const bf16x8*>(&pbuf[wave][swz64(lm * 64 + lkg * 16)]);
        #pragma unroll
        for (int db = 0; db < 4; ++db) {
            bf16x8 vf = *reinterpret_cast<const bf16x8*>(
                &vbuf[swz64((db * 16 + lm) * 64 + lkg * 16)]);
            oacc[db] = __builtin_amdgcn_mfma_f32_16x16x32_bf16(pf, vf, oacc[db], 0, 0, 0);
        }
    }

    #pragma unroll
    for (int r = 0; r < 4; ++r) {
        float s = osum[r];
        s += __shfl_xor(s, 1, 64);
        s += __shfl_xor(s, 2, 64);
        s += __shfl_xor(s, 4, 64);
        s += __shfl_xor(s, 8, 64);
        osum[r] = 1.f / s;
    }
    #pragma unroll
    for (int r = 0; r < 4; ++r) {
        int qpos = q0 + wave * 16 + lkg * 4 + r;
        if (qpos >= NTOK) continue;
        unsigned short* orow = outp + ((size_t)b * NTOK + qpos) * DIM + (size_t)head * HD;
        const unsigned short* qres = qpb + ((size_t)bh * NTOK + qpos) * HD;
        #pragma unroll
        for (int db = 0; db < 4; ++db) {
            int d = db * 16 + lm;
            float o = oacc[db][r] * osum[r];
            if (qpos > 0) o += bf2f(qres[d]);
            orow[d] = f2bf(o);
        }
    }
}

// ---------------------------------------------------------------------------
extern "C" void kernel_launch(void* const* d_in, const int* in_sizes, int n_in,
                              void* d_out, int out_size, void* d_ws, size_t ws_size,
                              hipStream_t stream) {
    const float* x     = (const float*)d_in[0];
    const float* Wqkv  = (const float*)d_in[1];
    const float* pqw   = (const float*)d_in[2];
    const float* pkw   = (const float*)d_in[3];
    const float* pvw   = (const float*)d_in[4];
    const float* gq    = (const float*)d_in[5];
    const float* bq    = (const float*)d_in[6];
    const float* gk    = (const float*)d_in[7];
    const float* bk    = (const float*)d_in[8];
    const float* gv    = (const float*)d_in[9];
    const float* bv    = (const float*)d_in[10];
    const float* rph   = (const float*)d_in[11];
    const float* rpw   = (const float*)d_in[12];
    const float* Wproj = (const float*)d_in[13];
    const float* bproj = (const float*)d_in[14];

    float* ws = (float*)d_ws;
    const size_t qkv_elems = (size_t)MROWS * THREE_DIM;              // 28,910,592
    const size_t qp_shorts = (size_t)NBH * NTOK * HD;                //  9,636,864
    const size_t kp_shorts = (size_t)NBH * NKEY * HD;                //  2,411,520
    const size_t vt_shorts = (size_t)NBH * HD * NKEYP;               //  2,433,024
    const size_t x_shorts  = (size_t)MROWS * DIM;                    //  9,636,864
    const size_t wq_shorts = (size_t)DIM * THREE_DIM;                //  1,769,472

    float* qkv = ws;                                   // fp32, dead after pools
    unsigned short* qpb  = (unsigned short*)(qkv + qkv_elems);   // bf16 q
    unsigned short* kp16 = qpb + qp_shorts;
    unsigned short* vt16 = kp16 + kp_shorts;
    unsigned short* xbf  = vt16 + vt_shorts;
    unsigned short* wqkvt = xbf + x_shorts;
    unsigned short* rphb = wqkvt + wq_shorts;          // 111*64 bf16
    unsigned short* rpwb = rphb + 7104;
    // carved out of the dead qkv region:
    unsigned short* attn_bf = (unsigned short*)qkv;    // [M][768] bf16
    float* relg = qkv + 10000000;                      // 8,429,568 floats
    unsigned short* wprojt = (unsigned short*)(qkv + 20000000);    // [768][768] bf16

    dim3 blk(256);

    // 0) bf16 conversions
    cvt_bf16<<<2048, blk, 0, stream>>>(x, xbf, (int)(x_shorts / 4));
    {
        dim3 g(THREE_DIM / 32, DIM / 32);
        transpose_bf16<<<g, blk, 0, stream>>>(Wqkv, wqkvt, DIM, THREE_DIM);
    }
    cvt_bf16<<<7, blk, 0, stream>>>(rph, rphb, 1776);
    cvt_bf16<<<7, blk, 0, stream>>>(rpw, rpwb, 1776);

    // 1) qkv = x @ Wqkv   (bf16 MFMA, fp32 out)
    {
        dim3 grid(THREE_DIM / 128, (MROWS + 127) / 128);
        gemm_mfma<<<grid, blk, 0, stream>>>(xbf, wqkvt, nullptr, qkv, MROWS, THREE_DIM, DIM);
    }

    // 2) pool + LN: q bf16 row-major, k bf16 row-major, v bf16 transposed
    pool_ln_kernel<<<NBH * NTOK, 64, 0, stream>>>(qkv, pqw, gq, bq, qpb,  0, 1, QH, QW, 1, 0);
    pool_ln_kernel<<<NBH * NKEY, 64, 0, stream>>>(qkv, pkw, gk, bk, kp16, 1, 2, 28, 28, 1, 0);
    pool_ln_kernel<<<NBH * NKEY, 64, 0, stream>>>(qkv, pvw, gv, bv, vt16, 2, 2, 28, 28, 2, NKEYP);

    // 3) rel-pos bias tables (MFMA) + proj weight transpose (qkv region dead)
    {
        dim3 g(56, (RELROWS + 255) / 256);
        rel_mfma<<<g, blk, 0, stream>>>(qpb, rphb, relg, 0);
        rel_mfma<<<g, blk, 0, stream>>>(qpb, rpwb, relg, 1);
    }
    {
        dim3 g(DIM / 32, DIM / 32);
        transpose_bf16<<<g, blk, 0, stream>>>(Wproj, wprojt, DIM, DIM);
    }

    // 4) MFMA flash attention (+bias, softmax, PV, residual) -> bf16
    attn_mfma<<<NBH * NQT, blk, 0, stream>>>(qpb, kp16, vt16, relg, attn_bf);

    // 5) out = attn_out @ Wproj + bproj   (bf16 MFMA, fp32 out)
    {
        dim3 grid(DIM / 128, (MROWS + 127) / 128);
        gemm_mfma<<<grid, blk, 0, stream>>>(attn_bf, wprojt, bproj, (float*)d_out, MROWS, DIM, DIM);
    }
}

// Round 5
// 395.868 us; speedup vs baseline: 19.7076x; 1.0552x over previous
//
#include <hip/hip_runtime.h>
#include <hip/hip_bf16.h>

// Problem constants (fixed by setup_inputs)
#define BATCH 4
#define NTOK 3137        // 1 + 56*56
#define DIM 768
#define NHEAD 12
#define HD 64
#define QH 56
#define QW 56
#define NKEY 785         // 1 + 28*28
#define NKEYPAD 800      // padded key count (25 x 32)
#define THREE_DIM 2304
#define MROWS (BATCH*NTOK)   // 12548
#define QTILE 64
#define NQT 50               // ceil(3137/64)
#define NBH 48               // BATCH*NHEAD
#define RELROWS (NBH*56)     // 2688
#define XD 128               // extended head dim (64 q + 28 relh + 28 relw + pad flag)

typedef __attribute__((ext_vector_type(8))) short bf16x8;
typedef __attribute__((ext_vector_type(4))) float f32x4;

__device__ __forceinline__ unsigned short f2bf(float f) {
    union { float f; unsigned u; } v; v.f = f;
    unsigned r = v.u + 0x7FFFu + ((v.u >> 16) & 1u);   // RNE
    return (unsigned short)(r >> 16);
}
__device__ __forceinline__ float bf2f(unsigned short s) {
    union { unsigned u; float f; } v; v.u = (unsigned)s << 16; return v.f;
}
// XOR swizzle (bijective) used by the P round-trip buffer
__device__ __forceinline__ int swz64(int x) { return x ^ (((x >> 6) & 7) << 4); }

__device__ __forceinline__ void gl16(const void* g, void* l) {
    __builtin_amdgcn_global_load_lds(
        (const __attribute__((address_space(1))) unsigned int*)g,
        (__attribute__((address_space(3))) unsigned int*)l, 16, 0, 0);
}

// ---------------------------------------------------------------------------
// fp32 -> bf16 elementwise (vectorized x4)
// ---------------------------------------------------------------------------
__global__ __launch_bounds__(256) void cvt_bf16(
    const float* __restrict__ in, unsigned short* __restrict__ outp, int n4)
{
    for (int i = blockIdx.x * 256 + threadIdx.x; i < n4; i += gridDim.x * 256) {
        float4 v = reinterpret_cast<const float4*>(in)[i];
        union { unsigned short s[4]; uint2 u; } o;
        o.s[0] = f2bf(v.x); o.s[1] = f2bf(v.y);
        o.s[2] = f2bf(v.z); o.s[3] = f2bf(v.w);
        reinterpret_cast<uint2*>(outp)[i] = o.u;
    }
}

// ---------------------------------------------------------------------------
// W[K][N] fp32 -> Wt[N][K] bf16 (32x32 LDS tile transpose)
// ---------------------------------------------------------------------------
__global__ __launch_bounds__(256) void transpose_bf16(
    const float* __restrict__ W, unsigned short* __restrict__ Wt, int K, int N)
{
    __shared__ float tile[32][33];
    int k0 = blockIdx.y * 32, n0 = blockIdx.x * 32;
    int t = threadIdx.x;
    int r = t >> 5, c = t & 31;
    #pragma unroll
    for (int p = 0; p < 4; ++p)
        tile[r + p * 8][c] = W[(size_t)(k0 + r + p * 8) * N + n0 + c];
    __syncthreads();
    #pragma unroll
    for (int p = 0; p < 4; ++p)
        Wt[(size_t)(n0 + r + p * 8) * K + k0 + c] = f2bf(tile[c][r + p * 8]);
}

// ---------------------------------------------------------------------------
// bf16 MFMA GEMM: C[M][N] = A[M][K]bf16 * Bt[N][K]bf16 (+bias).
// out_bf16: C written as bf16 (ushort), else fp32.
// ---------------------------------------------------------------------------
__global__ __launch_bounds__(256) void gemm_mfma(
    const unsigned short* __restrict__ A, const unsigned short* __restrict__ Bt,
    const float* __restrict__ bias, void* __restrict__ C,
    int M, int N, int K, int out_bf16)
{
    __shared__ __align__(16) char lds[16384];   // A[0..8K), B[8K..16K)
    int t = threadIdx.x;
    int wave = t >> 6, lane = t & 63;
    int lm = lane & 15, lkg = lane >> 4;
    int wr = wave >> 1, wc = wave & 1;
    int m0 = blockIdx.y * 128, n0 = blockIdx.x * 128;

    int o0 = wave * 2048 + lane * 16;
    int o1 = o0 + 1024;
    int r0 = o0 >> 6, s0 = ((o0 >> 4) & 3) ^ ((r0 >> 1) & 3);
    int r1 = o1 >> 6, s1 = ((o1 >> 4) & 3) ^ ((r1 >> 1) & 3);
    int ar0 = m0 + r0; if (ar0 >= M) ar0 = M - 1;
    int ar1 = m0 + r1; if (ar1 >= M) ar1 = M - 1;

    const unsigned short* ap0 = A + (size_t)ar0 * K + s0 * 8;
    const unsigned short* ap1 = A + (size_t)ar1 * K + s1 * 8;
    const unsigned short* bp0 = Bt + (size_t)(n0 + r0) * K + s0 * 8;
    const unsigned short* bp1 = Bt + (size_t)(n0 + r1) * K + s1 * 8;

    char* la0 = &lds[wave * 2048];
    char* la1 = &lds[wave * 2048 + 1024];
    char* lb0 = &lds[8192 + wave * 2048];
    char* lb1 = &lds[8192 + wave * 2048 + 1024];

    f32x4 acc[4][4] = {};

    for (int k0 = 0; k0 < K; k0 += 32) {
        gl16(ap0, la0); gl16(ap1, la1);
        gl16(bp0, lb0); gl16(bp1, lb1);
        ap0 += 32; ap1 += 32; bp0 += 32; bp1 += 32;
        __syncthreads();

        bf16x8 af[4], bfr[4];
        #pragma unroll
        for (int m = 0; m < 4; ++m) {
            int row = wr * 64 + m * 16 + lm;
            af[m] = *reinterpret_cast<const bf16x8*>(
                &lds[row * 64 + ((lkg ^ ((row >> 1) & 3)) << 4)]);
        }
        #pragma unroll
        for (int n = 0; n < 4; ++n) {
            int row = wc * 64 + n * 16 + lm;
            bfr[n] = *reinterpret_cast<const bf16x8*>(
                &lds[8192 + row * 64 + ((lkg ^ ((row >> 1) & 3)) << 4)]);
        }
        #pragma unroll
        for (int m = 0; m < 4; ++m)
            #pragma unroll
            for (int n = 0; n < 4; ++n)
                acc[m][n] = __builtin_amdgcn_mfma_f32_16x16x32_bf16(
                    af[m], bfr[n], acc[m][n], 0, 0, 0);
        __syncthreads();
    }

    #pragma unroll
    for (int n = 0; n < 4; ++n) {
        int col = n0 + wc * 64 + n * 16 + lm;
        float bval = bias ? bias[col] : 0.f;
        #pragma unroll
        for (int m = 0; m < 4; ++m) {
            int row = m0 + wr * 64 + m * 16 + lkg * 4;
            #pragma unroll
            for (int r = 0; r < 4; ++r) {
                if (row + r < M) {
                    float o = acc[m][n][r] + bval;
                    if (out_bf16)
                        ((unsigned short*)C)[(size_t)(row + r) * N + col] = f2bf(o);
                    else
                        ((float*)C)[(size_t)(row + r) * N + col] = o;
                }
            }
        }
    }
}

// ---------------------------------------------------------------------------
// Depthwise 3x3 pool + LayerNorm, reading bf16 qkv.
// mode 3: q-ext rows [bh][pos][128]: col d = q*0.125, col 64..127 = 0 except
//         col 120 = -30 (pad-key suppressor). rel_mfma fills 64..119 later.
// mode 1: k-ext rows [bh][pos][128]: col d = k, col 64+kh = 1, col 92+kw = 1,
//         pad rows (pos>=npos): zeros + col 120 = 1.
// mode 2: v transposed [bh][64][NKEYPAD], pad cols zero.
// ---------------------------------------------------------------------------
__global__ __launch_bounds__(64) void pool_ln_kernel(
    const unsigned short* __restrict__ qkvb, const float* __restrict__ w,
    const float* __restrict__ g, const float* __restrict__ beta,
    unsigned short* __restrict__ outp, int qi, int stride, int OH, int OW,
    int mode, int npos_grid)
{
    int npos = 1 + OH * OW;
    int bid = blockIdx.x;
    int pos = bid % npos_grid;
    int bh  = bid / npos_grid;
    int head = bh % NHEAD;
    int b    = bh / NHEAD;
    int d = threadIdx.x;

    if (pos >= npos) {           // pad rows (k/v only); uniform per block
        if (mode == 1) {
            unsigned short* row = outp + ((size_t)bh * NKEYPAD + pos) * XD;
            row[d] = 0;
            row[64 + d] = (d == 56) ? 0x3F80 : 0;   // pad-flag channel = 1.0
        } else {                 // mode 2
            outp[((size_t)bh * HD + d) * NKEYPAD + pos] = 0;
        }
        return;
    }

    const size_t base = (size_t)b * NTOK * THREE_DIM + (size_t)qi * DIM + (size_t)head * HD + d;

    float val;
    if (pos == 0) {
        val = bf2f(qkvb[base]);
    } else {
        int oh = (pos - 1) / OW, ow = (pos - 1) % OW;
        float acc = 0.f;
        #pragma unroll
        for (int r = 0; r < 3; ++r) {
            int ih = oh * stride + r - 1;
            if (ih < 0 || ih >= QH) continue;
            #pragma unroll
            for (int c = 0; c < 3; ++c) {
                int iw = ow * stride + c - 1;
                if (iw < 0 || iw >= QW) continue;
                int n = 1 + ih * QW + iw;
                acc += bf2f(qkvb[base + (size_t)n * THREE_DIM]) * w[d * 9 + r * 3 + c];
            }
        }
        val = acc;
    }

    float mu = val;
    #pragma unroll
    for (int off = 32; off > 0; off >>= 1) mu += __shfl_xor(mu, off, 64);
    mu *= (1.f / 64.f);
    float dv = val - mu;
    float var = dv * dv;
    #pragma unroll
    for (int off = 32; off > 0; off >>= 1) var += __shfl_xor(var, off, 64);
    var *= (1.f / 64.f);
    float o = dv * rsqrtf(var + 1e-5f) * g[d] + beta[d];

    if (mode == 3) {
        unsigned short* row = outp + ((size_t)bh * NTOK + pos) * XD;
        row[d] = f2bf(o * 0.125f);                      // scale folded (exact)
        row[64 + d] = (d == 56) ? f2bf(-30.f) : 0;      // ext zeros + suppressor
    } else if (mode == 1) {
        unsigned short* row = outp + ((size_t)bh * NKEYPAD + pos) * XD;
        row[d] = f2bf(o);
        unsigned short ext = 0;
        if (pos > 0) {
            int kh = (pos - 1) / 28, kw = (pos - 1) % 28;
            if ((d < 28 && d == kh) || (d >= 28 && d < 56 && d - 28 == kw))
                ext = 0x3F80;   // 1.0 bf16
        }
        row[64 + d] = ext;
    } else {
        outp[((size_t)bh * HD + d) * NKEYPAD + pos] = f2bf(o);
    }
}

// ---------------------------------------------------------------------------
// MFMA rel-pos dots, written as bf16 into the Q-ext columns of qpx.
// mode 0 (rel_h): rows=(bh,w) at fixed h=X, cols 64..91
// mode 1 (rel_w): rows=(bh,h) at fixed w=X, cols 92..119
// qpx q-values are pre-scaled by 0.125, so results are scaled by 8.
// ---------------------------------------------------------------------------
__global__ __launch_bounds__(256) void rel_mfma(
    const unsigned short* __restrict__ qpx, const unsigned short* __restrict__ rtab,
    unsigned short* __restrict__ qpx_out, int mode)
{
    __shared__ char bbuf[4096];     // [32 rows][64 bf16], XOR-swizzled
    int X = blockIdx.x;
    int m0 = blockIdx.y * 256;
    int t = threadIdx.x;
    int wave = t >> 6, lane = t & 63;
    int lm = lane & 15, lkg = lane >> 4;

    {
        int row = t >> 3, c8 = t & 7;
        int4 val = {0, 0, 0, 0};
        if (row < 28) {
            int dh = X - 2 * row + 54;              // in [0, 110)
            val = *reinterpret_cast<const int4*>(rtab + (size_t)dh * HD + c8 * 8);
        }
        *reinterpret_cast<int4*>(&bbuf[row * 128 + ((c8 * 16) ^ ((row & 7) << 4))]) = val;
    }
    __syncthreads();

    int rbase = m0 + wave * 64 + lm;
    f32x4 acc[4][2] = {};
    #pragma unroll
    for (int kc = 0; kc < 2; ++kc) {
        bf16x8 bfrag[2];
        #pragma unroll
        for (int nb = 0; nb < 2; ++nb) {
            int row = nb * 16 + lm;
            bfrag[nb] = *reinterpret_cast<const bf16x8*>(
                &bbuf[row * 128 + (((kc * 4 + lkg) * 16) ^ ((row & 7) << 4))]);
        }
        #pragma unroll
        for (int m = 0; m < 4; ++m) {
            int rho = rbase + m * 16; if (rho > RELROWS - 1) rho = RELROWS - 1;
            int bh = rho / 56, rem = rho % 56;
            int pos1 = (mode == 0) ? X * 56 + rem : rem * 56 + X;
            const unsigned short* qsrc =
                qpx + ((size_t)bh * NTOK + 1 + pos1) * XD + kc * 32 + lkg * 8;
            bf16x8 af = *reinterpret_cast<const bf16x8*>(qsrc);
            acc[m][0] = __builtin_amdgcn_mfma_f32_16x16x32_bf16(af, bfrag[0], acc[m][0], 0, 0, 0);
            acc[m][1] = __builtin_amdgcn_mfma_f32_16x16x32_bf16(af, bfrag[1], acc[m][1], 0, 0, 0);
        }
    }

    #pragma unroll
    for (int m = 0; m < 4; ++m) {
        #pragma unroll
        for (int r = 0; r < 4; ++r) {
            int rho = m0 + wave * 64 + m * 16 + lkg * 4 + r;
            if (rho >= RELROWS) continue;
            int bh = rho / 56, rem = rho % 56;
            int pos1 = (mode == 0) ? X * 56 + rem : rem * 56 + X;
            unsigned short* dst =
                qpx_out + ((size_t)bh * NTOK + 1 + pos1) * XD + 64 + mode * 28;
            dst[lm] = f2bf(acc[m][0][r] * 8.f);             // un-scale
            if (lm < 12) dst[16 + lm] = f2bf(acc[m][1][r] * 8.f);
        }
    }
}

// ---------------------------------------------------------------------------
// MFMA flash attention with bias folded into extended K-dim (128).
// S = Qext . Kext = 0.125*q.k + relh + relw (pad keys -> -30 -> exp ~ 0).
// Block = 64 q-rows (4 waves x 16), K-steps of 32, no tail, no masks.
// ---------------------------------------------------------------------------
__global__ __launch_bounds__(256) void attn_mfma(
    const unsigned short* __restrict__ qpx, const unsigned short* __restrict__ kpx,
    const unsigned short* __restrict__ vt, unsigned short* __restrict__ outp)
{
    __shared__ __align__(16) char kbuf[8192];   // Kext tile [32][128] bf16, swizzled
    __shared__ __align__(16) char vbuf[4096];   // Vt tile  [64][32]  bf16, swizzled
    __shared__ __align__(16) char pbuf[4][1024];// per-wave P [16][32] bf16, swizzled

    int bid = blockIdx.x;
    int tile = bid % NQT;
    int bh = bid / NQT;
    int head = bh % NHEAD, b = bh / NHEAD;
    int q0 = tile * QTILE;
    int t = threadIdx.x;
    int wave = t >> 6, lane = t & 63;
    int lm = lane & 15, lkg = lane >> 4;

    const unsigned short* kb  = kpx + (size_t)bh * NKEYPAD * XD;
    const unsigned short* vtb = vt + (size_t)bh * HD * NKEYPAD;

    // Q fragments: 4 chunks of 32 k-dims
    bf16x8 qf[4] = {};
    int qrow = q0 + wave * 16 + lm;
    if (qrow < NTOK) {
        const unsigned short* qs = qpx + ((size_t)bh * NTOK + qrow) * XD + lkg * 8;
        qf[0] = *reinterpret_cast<const bf16x8*>(qs);
        qf[1] = *reinterpret_cast<const bf16x8*>(qs + 32);
        qf[2] = *reinterpret_cast<const bf16x8*>(qs + 64);
        qf[3] = *reinterpret_cast<const bf16x8*>(qs + 96);
    }

    f32x4 oacc[4] = {};
    float osum[4] = {0.f, 0.f, 0.f, 0.f};

    // staging sources (pre-swizzled so linear gl_lds dest => swizzled layout)
    int kr0 = t >> 4;                       // rows 0..15
    int ks0 = (t & 15) ^ (kr0 & 7);
    int kr1 = kr0 + 16;                     // rows 16..31 ((kr1&7)==(kr0&7)... no: kr1&7 = kr0&7? 16+r: &7 differs when r>=8? (r+16)&7 == r&7. yes same)
    const unsigned short* kp0 = kb + (size_t)kr0 * XD + ks0 * 8;
    const unsigned short* kp1 = kb + (size_t)kr1 * XD + ks0 * 8;
    int vr = t >> 2;                        // rows 0..63
    int vs = (t & 3) ^ ((vr >> 1) & 3);
    const unsigned short* vp0 = vtb + (size_t)vr * NKEYPAD + vs * 8;
    char* kdst0 = &kbuf[wave * 1024];
    char* kdst1 = &kbuf[4096 + wave * 1024];
    char* vdst  = &vbuf[wave * 1024];

    for (int j0 = 0; j0 < NKEYPAD; j0 += 32) {
        __syncthreads();                    // previous tile fully consumed
        gl16(kp0, kdst0);
        gl16(kp1, kdst1);
        gl16(vp0, vdst);
        kp0 += 32 * XD; kp1 += 32 * XD; vp0 += 32;
        __syncthreads();                    // staging complete (vmcnt drained)

        // QK^T over 128 ext dims: S[16 q x 32 k] per wave
        f32x4 acc0 = {0.f, 0.f, 0.f, 0.f}, acc1 = {0.f, 0.f, 0.f, 0.f};
        #pragma unroll
        for (int kc = 0; kc < 4; ++kc) {
            int sl = (kc * 4 + lkg) ^ (lm & 7);
            bf16x8 kf0 = *reinterpret_cast<const bf16x8*>(&kbuf[lm * 256 + sl * 16]);
            acc0 = __builtin_amdgcn_mfma_f32_16x16x32_bf16(qf[kc], kf0, acc0, 0, 0, 0);
            bf16x8 kf1 = *reinterpret_cast<const bf16x8*>(&kbuf[(16 + lm) * 256 + sl * 16]);
            acc1 = __builtin_amdgcn_mfma_f32_16x16x32_bf16(qf[kc], kf1, acc1, 0, 0, 0);
        }

        // epilogue: exp only (scores complete, pads self-suppressed)
        #pragma unroll
        for (int nb = 0; nb < 2; ++nb) {
            f32x4 a = nb ? acc1 : acc0;
            #pragma unroll
            for (int r = 0; r < 4; ++r) {
                float e = __expf(a[r]);
                osum[r] += e;
                int baddr = (lkg * 4 + r) * 64 + (nb * 16 + lm) * 2;
                *reinterpret_cast<unsigned short*>(&pbuf[wave][swz64(baddr)]) = f2bf(e);
            }
        }

        // PV: O += P[16x32] * Vt
        bf16x8 pf = *reinterpret_cast<const bf16x8*>(&pbuf[wave][swz64(lm * 64 + lkg * 16)]);
        #pragma unroll
        for (int db = 0; db < 4; ++db) {
            int row = db * 16 + lm;
            bf16x8 vf = *reinterpret_cast<const bf16x8*>(
                &vbuf[row * 64 + ((lkg ^ ((row >> 1) & 3)) << 4)]);
            oacc[db] = __builtin_amdgcn_mfma_f32_16x16x32_bf16(pf, vf, oacc[db], 0, 0, 0);
        }
    }

    #pragma unroll
    for (int r = 0; r < 4; ++r) {
        float s = osum[r];
        s += __shfl_xor(s, 1, 64);
        s += __shfl_xor(s, 2, 64);
        s += __shfl_xor(s, 4, 64);
        s += __shfl_xor(s, 8, 64);
        osum[r] = 1.f / s;
    }
    #pragma unroll
    for (int r = 0; r < 4; ++r) {
        int qpos = q0 + wave * 16 + lkg * 4 + r;
        if (qpos >= NTOK) continue;
        unsigned short* orow = outp + ((size_t)b * NTOK + qpos) * DIM + (size_t)head * HD;
        const unsigned short* qres = qpx + ((size_t)bh * NTOK + qpos) * XD;
        #pragma unroll
        for (int db = 0; db < 4; ++db) {
            int d = db * 16 + lm;
            float o = oacc[db][r] * osum[r];
            if (qpos > 0) o += bf2f(qres[d]) * 8.f;   // residual (q was x0.125)
            orow[d] = f2bf(o);
        }
    }
}

// ---------------------------------------------------------------------------
extern "C" void kernel_launch(void* const* d_in, const int* in_sizes, int n_in,
                              void* d_out, int out_size, void* d_ws, size_t ws_size,
                              hipStream_t stream) {
    const float* x     = (const float*)d_in[0];
    const float* Wqkv  = (const float*)d_in[1];
    const float* pqw   = (const float*)d_in[2];
    const float* pkw   = (const float*)d_in[3];
    const float* pvw   = (const float*)d_in[4];
    const float* gq    = (const float*)d_in[5];
    const float* bq    = (const float*)d_in[6];
    const float* gk    = (const float*)d_in[7];
    const float* bk    = (const float*)d_in[8];
    const float* gv    = (const float*)d_in[9];
    const float* bv    = (const float*)d_in[10];
    const float* rph   = (const float*)d_in[11];
    const float* rpw   = (const float*)d_in[12];
    const float* Wproj = (const float*)d_in[13];
    const float* bproj = (const float*)d_in[14];

    unsigned short* qkvb  = (unsigned short*)d_ws;                 // [M][2304] bf16
    unsigned short* qpx   = qkvb + (size_t)MROWS * THREE_DIM;      // [48][3137][128]
    unsigned short* kpx   = qpx + (size_t)NBH * NTOK * XD;         // [48][800][128]
    unsigned short* vt16  = kpx + (size_t)NBH * NKEYPAD * XD;      // [48][64][800]
    unsigned short* xbf   = vt16 + (size_t)NBH * HD * NKEYPAD;     // [M][768]
    unsigned short* wqkvt = xbf + (size_t)MROWS * DIM;             // [2304][768]
    unsigned short* wprojt= wqkvt + (size_t)DIM * THREE_DIM;       // [768][768]
    unsigned short* rphb  = wprojt + (size_t)DIM * DIM;            // [111][64]
    unsigned short* rpwb  = rphb + 7104;
    unsigned short* attn_bf = qkvb;            // alias (qkvb dead after pools)

    dim3 blk(256);

    // 0) bf16 conversions
    cvt_bf16<<<2048, blk, 0, stream>>>(x, xbf, (int)((size_t)MROWS * DIM / 4));
    {
        dim3 g(THREE_DIM / 32, DIM / 32);
        transpose_bf16<<<g, blk, 0, stream>>>(Wqkv, wqkvt, DIM, THREE_DIM);
    }
    {
        dim3 g(DIM / 32, DIM / 32);
        transpose_bf16<<<g, blk, 0, stream>>>(Wproj, wprojt, DIM, DIM);
    }
    cvt_bf16<<<7, blk, 0, stream>>>(rph, rphb, 1776);
    cvt_bf16<<<7, blk, 0, stream>>>(rpw, rpwb, 1776);

    // 1) qkv = x @ Wqkv   (bf16 MFMA, bf16 out)
    {
        dim3 grid(THREE_DIM / 128, (MROWS + 127) / 128);
        gemm_mfma<<<grid, blk, 0, stream>>>(xbf, wqkvt, nullptr, qkvb,
                                            MROWS, THREE_DIM, DIM, 1);
    }

    // 2) pool + LN: q-ext, k-ext (with onehot + pad rows), v transposed+padded
    pool_ln_kernel<<<NBH * NTOK, 64, 0, stream>>>(qkvb, pqw, gq, bq, qpx,  0, 1, QH, QW, 3, NTOK);
    pool_ln_kernel<<<NBH * NKEYPAD, 64, 0, stream>>>(qkvb, pkw, gk, bk, kpx, 1, 2, 28, 28, 1, NKEYPAD);
    pool_ln_kernel<<<NBH * NKEYPAD, 64, 0, stream>>>(qkvb, pvw, gv, bv, vt16, 2, 2, 28, 28, 2, NKEYPAD);

    // 3) rel-pos dots -> Q-ext columns (bf16, in-place into qpx)
    {
        dim3 g(56, (RELROWS + 255) / 256);
        rel_mfma<<<g, blk, 0, stream>>>(qpx, rphb, qpx, 0);
        rel_mfma<<<g, blk, 0, stream>>>(qpx, rpwb, qpx, 1);
    }

    // 4) MFMA flash attention (bias folded) -> bf16
    attn_mfma<<<NBH * NQT, blk, 0, stream>>>(qpx, kpx, vt16, attn_bf);

    // 5) out = attn_out @ Wproj + bproj   (bf16 MFMA, fp32 out)
    {
        dim3 grid(DIM / 128, (MROWS + 127) / 128);
        gemm_mfma<<<grid, blk, 0, stream>>>(attn_bf, wprojt, bproj, d_out,
                                            MROWS, DIM, DIM, 0);
    }
}

// Round 6
// 334.412 us; speedup vs baseline: 23.3294x; 1.1838x over previous
//
#include <hip/hip_runtime.h>
#include <hip/hip_bf16.h>

// Problem constants (fixed by setup_inputs)
#define BATCH 4
#define NTOK 3137        // 1 + 56*56
#define DIM 768
#define NHEAD 12
#define HD 64
#define QH 56
#define QW 56
#define NKEY 785         // 1 + 28*28
#define NKEYPAD 800      // padded key count (25 x 32)
#define THREE_DIM 2304
#define MROWS (BATCH*NTOK)   // 12548
#define QTILE 64
#define NQT 50               // ceil(3137/64)
#define NBH 48               // BATCH*NHEAD
#define RELROWS (NBH*56)     // 2688
#define XD 128               // extended head dim (64 q + 28 relh + 28 relw + pad flag)

typedef __attribute__((ext_vector_type(8))) short bf16x8;
typedef __attribute__((ext_vector_type(4))) float f32x4;

__device__ __forceinline__ unsigned short f2bf(float f) {
    union { float f; unsigned u; } v; v.f = f;
    unsigned r = v.u + 0x7FFFu + ((v.u >> 16) & 1u);   // RNE
    return (unsigned short)(r >> 16);
}
__device__ __forceinline__ float bf2f(unsigned short s) {
    union { unsigned u; float f; } v; v.u = (unsigned)s << 16; return v.f;
}
// XOR swizzle (bijective) used by the P round-trip buffer
__device__ __forceinline__ int swz64(int x) { return x ^ (((x >> 6) & 7) << 4); }

__device__ __forceinline__ void gl16(const void* g, void* l) {
    __builtin_amdgcn_global_load_lds(
        (const __attribute__((address_space(1))) unsigned int*)g,
        (__attribute__((address_space(3))) unsigned int*)l, 16, 0, 0);
}

// ---------------------------------------------------------------------------
// fp32 -> bf16 elementwise (vectorized x4)
// ---------------------------------------------------------------------------
__global__ __launch_bounds__(256) void cvt_bf16(
    const float* __restrict__ in, unsigned short* __restrict__ outp, int n4)
{
    for (int i = blockIdx.x * 256 + threadIdx.x; i < n4; i += gridDim.x * 256) {
        float4 v = reinterpret_cast<const float4*>(in)[i];
        union { unsigned short s[4]; uint2 u; } o;
        o.s[0] = f2bf(v.x); o.s[1] = f2bf(v.y);
        o.s[2] = f2bf(v.z); o.s[3] = f2bf(v.w);
        reinterpret_cast<uint2*>(outp)[i] = o.u;
    }
}

// ---------------------------------------------------------------------------
// W[K][N] fp32 -> Wt[N][K] bf16 (32x32 LDS tile transpose)
// ---------------------------------------------------------------------------
__global__ __launch_bounds__(256) void transpose_bf16(
    const float* __restrict__ W, unsigned short* __restrict__ Wt, int K, int N)
{
    __shared__ float tile[32][33];
    int k0 = blockIdx.y * 32, n0 = blockIdx.x * 32;
    int t = threadIdx.x;
    int r = t >> 5, c = t & 31;
    #pragma unroll
    for (int p = 0; p < 4; ++p)
        tile[r + p * 8][c] = W[(size_t)(k0 + r + p * 8) * N + n0 + c];
    __syncthreads();
    #pragma unroll
    for (int p = 0; p < 4; ++p)
        Wt[(size_t)(n0 + r + p * 8) * K + k0 + c] = f2bf(tile[c][r + p * 8]);
}

// ---------------------------------------------------------------------------
// bf16 MFMA GEMM: C[M][N] = A[M][K]bf16 * Bt[N][K]bf16 (+bias).
// 128x128 tile, BK=32, 4 waves, 2-phase prefetch double-buffer,
// bijective XCD-aware block swizzle. out_bf16 selects bf16/fp32 C.
// ---------------------------------------------------------------------------
__global__ __launch_bounds__(256) void gemm_mfma(
    const unsigned short* __restrict__ A, const unsigned short* __restrict__ Bt,
    const float* __restrict__ bias, void* __restrict__ C,
    int M, int N, int K, int out_bf16)
{
    __shared__ __align__(16) char lds[32768];   // buf0: A[0,8K) B[8K,16K); buf1: +16K
    int t = threadIdx.x;
    int wave = t >> 6, lane = t & 63;
    int lm = lane & 15, lkg = lane >> 4;
    int wr = wave >> 1, wc = wave & 1;

    // bijective XCD remap (m204)
    int gx = gridDim.x;
    int nwg = gx * gridDim.y;
    int lin = blockIdx.y * gx + blockIdx.x;
    int qq = nwg >> 3, rr = nwg & 7;
    int xcd = lin & 7, idx = lin >> 3;
    int newlin = (xcd < rr ? xcd * (qq + 1) : rr * (qq + 1) + (xcd - rr) * qq) + idx;
    int m0 = (newlin / gx) * 128, n0 = (newlin % gx) * 128;

    // staging roles: two 16B chunks per matrix per thread, pre-swizzled source
    int o0 = wave * 2048 + lane * 16;
    int o1 = o0 + 1024;
    int r0 = o0 >> 6, s0 = ((o0 >> 4) & 3) ^ ((r0 >> 1) & 3);
    int r1 = o1 >> 6, s1 = ((o1 >> 4) & 3) ^ ((r1 >> 1) & 3);
    int ar0 = m0 + r0; if (ar0 >= M) ar0 = M - 1;
    int ar1 = m0 + r1; if (ar1 >= M) ar1 = M - 1;

    const unsigned short* ap0 = A + (size_t)ar0 * K + s0 * 8;
    const unsigned short* ap1 = A + (size_t)ar1 * K + s1 * 8;
    const unsigned short* bp0 = Bt + (size_t)(n0 + r0) * K + s0 * 8;
    const unsigned short* bp1 = Bt + (size_t)(n0 + r1) * K + s1 * 8;

    int oa0 = o0, oa1 = o1, ob0 = 8192 + o0, ob1 = 8192 + o1;

    f32x4 acc[4][4] = {};
    const int nt = K >> 5;

    // prologue: stage tile 0 into buffer 0
    gl16(ap0, &lds[oa0]); gl16(ap1, &lds[oa1]);
    gl16(bp0, &lds[ob0]); gl16(bp1, &lds[ob1]);
    ap0 += 32; ap1 += 32; bp0 += 32; bp1 += 32;
    __syncthreads();

    for (int tt = 0; tt < nt; ++tt) {
        int cb = (tt & 1) << 14;
        if (tt + 1 < nt) {
            int nb2 = ((tt + 1) & 1) << 14;
            gl16(ap0, &lds[nb2 + oa0]); gl16(ap1, &lds[nb2 + oa1]);
            gl16(bp0, &lds[nb2 + ob0]); gl16(bp1, &lds[nb2 + ob1]);
            ap0 += 32; ap1 += 32; bp0 += 32; bp1 += 32;
        }
        bf16x8 af[4], bfr[4];
        #pragma unroll
        for (int m = 0; m < 4; ++m) {
            int row = wr * 64 + m * 16 + lm;
            af[m] = *reinterpret_cast<const bf16x8*>(
                &lds[cb + row * 64 + ((lkg ^ ((row >> 1) & 3)) << 4)]);
        }
        #pragma unroll
        for (int n = 0; n < 4; ++n) {
            int row = wc * 64 + n * 16 + lm;
            bfr[n] = *reinterpret_cast<const bf16x8*>(
                &lds[cb + 8192 + row * 64 + ((lkg ^ ((row >> 1) & 3)) << 4)]);
        }
        #pragma unroll
        for (int m = 0; m < 4; ++m)
            #pragma unroll
            for (int n = 0; n < 4; ++n)
                acc[m][n] = __builtin_amdgcn_mfma_f32_16x16x32_bf16(
                    af[m], bfr[n], acc[m][n], 0, 0, 0);
        if (tt + 1 < nt) __syncthreads();
    }

    #pragma unroll
    for (int n = 0; n < 4; ++n) {
        int col = n0 + wc * 64 + n * 16 + lm;
        float bval = bias ? bias[col] : 0.f;
        #pragma unroll
        for (int m = 0; m < 4; ++m) {
            int row = m0 + wr * 64 + m * 16 + lkg * 4;
            #pragma unroll
            for (int r = 0; r < 4; ++r) {
                if (row + r < M) {
                    float o = acc[m][n][r] + bval;
                    if (out_bf16)
                        ((unsigned short*)C)[(size_t)(row + r) * N + col] = f2bf(o);
                    else
                        ((float*)C)[(size_t)(row + r) * N + col] = o;
                }
            }
        }
    }
}

// ---------------------------------------------------------------------------
// Row-tiled depthwise 3x3 pool + LayerNorm. One block per (bh, out-row).
// Stages the 3 input rows (3x56x64 bf16) in LDS; 4 waves each handle
// out-positions ow = wave, wave+4, ... Each position's 64 channels = 64 lanes.
// mode 3: q-ext [bh][pos][128] (q*0.125, ext zeros, [120]=-30)
// mode 1: k-ext [bh][pos][128] (k, onehot(kh)/onehot(kw))
// mode 2: v^T   [bh][64][NKEYPAD]
// ---------------------------------------------------------------------------
__global__ __launch_bounds__(256) void pool_ln_rows(
    const unsigned short* __restrict__ qkvb, const float* __restrict__ w,
    const float* __restrict__ g, const float* __restrict__ beta,
    unsigned short* __restrict__ outp, int qi, int stride, int OH, int OW,
    int mode)
{
    __shared__ unsigned short ibuf[3 * 56 * 64];   // 21.5 KB
    int bid = blockIdx.x;
    int orow = bid % OH;
    int bh = bid / OH;
    int head = bh % NHEAD, b = bh / NHEAD;
    int t = threadIdx.x;
    int wave = t >> 6, lane = t & 63;

    const unsigned short* src =
        qkvb + (size_t)b * NTOK * THREE_DIM + (size_t)qi * DIM + (size_t)head * HD;

    // stage rows ih = orow*stride-1 .. +1 (zero-padded), 4B per thread-iter
    for (int i = t; i < 3 * 56 * 32; i += 256) {
        int pair = i >> 5, off = i & 31;
        int r = pair / 56, iw = pair % 56;
        int ih = orow * stride + r - 1;
        unsigned v = 0;
        if (ih >= 0 && ih < QH)
            v = *reinterpret_cast<const unsigned*>(
                src + (size_t)(1 + ih * QW + iw) * THREE_DIM + off * 2);
        *reinterpret_cast<unsigned*>(&ibuf[pair * 64 + off * 2]) = v;
    }

    float wreg[9];
    #pragma unroll
    for (int k = 0; k < 9; ++k) wreg[k] = w[lane * 9 + k];
    float gl = g[lane], bl = beta[lane];
    __syncthreads();

    int ntask = OW + ((orow == 0) ? 1 : 0);    // extra task: cls (pos 0)
    for (int task = wave; task < ntask; task += 4) {
        float val;
        int pos;
        if (task == OW) {                      // cls token
            val = bf2f(src[lane]);             // n = 0 row
            pos = 0;
        } else {
            int ow = task;
            float acc = 0.f;
            #pragma unroll
            for (int r = 0; r < 3; ++r) {
                #pragma unroll
                for (int c = 0; c < 3; ++c) {
                    int iwc = ow * stride + c - 1;
                    if (iwc < 0 || iwc >= QW) continue;
                    acc += bf2f(ibuf[(r * 56 + iwc) * 64 + lane]) * wreg[r * 3 + c];
                }
            }
            val = acc;
            pos = 1 + orow * OW + ow;
        }

        float mu = val;
        #pragma unroll
        for (int off = 32; off > 0; off >>= 1) mu += __shfl_xor(mu, off, 64);
        mu *= (1.f / 64.f);
        float dv = val - mu;
        float var = dv * dv;
        #pragma unroll
        for (int off = 32; off > 0; off >>= 1) var += __shfl_xor(var, off, 64);
        var *= (1.f / 64.f);
        float o = dv * rsqrtf(var + 1e-5f) * gl + bl;

        if (mode == 3) {
            unsigned short* row = outp + ((size_t)bh * NTOK + pos) * XD;
            row[lane] = f2bf(o * 0.125f);
            row[64 + lane] = (lane == 56) ? f2bf(-30.f) : 0;
        } else if (mode == 1) {
            unsigned short* row = outp + ((size_t)bh * NKEYPAD + pos) * XD;
            row[lane] = f2bf(o);
            unsigned short ext = 0;
            if (pos > 0) {
                int kh = (pos - 1) / 28, kw = (pos - 1) % 28;
                if ((lane < 28 && lane == kh) ||
                    (lane >= 28 && lane < 56 && lane - 28 == kw))
                    ext = 0x3F80;   // 1.0 bf16
            }
            row[64 + lane] = ext;
        } else {
            outp[((size_t)bh * HD + lane) * NKEYPAD + pos] = f2bf(o);
        }
    }
}

// ---------------------------------------------------------------------------
// Pad rows (785..799): k-ext rows = pad-flag onehot; v^T pad cols = 0.
// ---------------------------------------------------------------------------
__global__ __launch_bounds__(64) void pad_kv(
    unsigned short* __restrict__ kpx, unsigned short* __restrict__ vt16)
{
    int bh = blockIdx.x;
    int t = threadIdx.x;
    for (int pos = NKEY; pos < NKEYPAD; ++pos) {
        unsigned short* row = kpx + ((size_t)bh * NKEYPAD + pos) * XD;
        row[t] = 0;
        row[64 + t] = (t == 56) ? 0x3F80 : 0;
        vt16[((size_t)bh * HD + t) * NKEYPAD + pos] = 0;
    }
}

// ---------------------------------------------------------------------------
// MFMA rel-pos dots, written as bf16 into the Q-ext columns of qpx.
// mode 0 (rel_h): rows=(bh,w) at fixed h=X, cols 64..91
// mode 1 (rel_w): rows=(bh,h) at fixed w=X, cols 92..119
// qpx q-values are pre-scaled by 0.125, so results are scaled by 8.
// ---------------------------------------------------------------------------
__global__ __launch_bounds__(256) void rel_mfma(
    const unsigned short* __restrict__ qpx, const unsigned short* __restrict__ rtab,
    unsigned short* __restrict__ qpx_out, int mode)
{
    __shared__ char bbuf[4096];     // [32 rows][64 bf16], XOR-swizzled
    int X = blockIdx.x;
    int m0 = blockIdx.y * 256;
    int t = threadIdx.x;
    int wave = t >> 6, lane = t & 63;
    int lm = lane & 15, lkg = lane >> 4;

    {
        int row = t >> 3, c8 = t & 7;
        int4 val = {0, 0, 0, 0};
        if (row < 28) {
            int dh = X - 2 * row + 54;              // in [0, 110)
            val = *reinterpret_cast<const int4*>(rtab + (size_t)dh * HD + c8 * 8);
        }
        *reinterpret_cast<int4*>(&bbuf[row * 128 + ((c8 * 16) ^ ((row & 7) << 4))]) = val;
    }
    __syncthreads();

    int rbase = m0 + wave * 64 + lm;
    f32x4 acc[4][2] = {};
    #pragma unroll
    for (int kc = 0; kc < 2; ++kc) {
        bf16x8 bfrag[2];
        #pragma unroll
        for (int nb = 0; nb < 2; ++nb) {
            int row = nb * 16 + lm;
            bfrag[nb] = *reinterpret_cast<const bf16x8*>(
                &bbuf[row * 128 + (((kc * 4 + lkg) * 16) ^ ((row & 7) << 4))]);
        }
        #pragma unroll
        for (int m = 0; m < 4; ++m) {
            int rho = rbase + m * 16; if (rho > RELROWS - 1) rho = RELROWS - 1;
            int bh = rho / 56, rem = rho % 56;
            int pos1 = (mode == 0) ? X * 56 + rem : rem * 56 + X;
            const unsigned short* qsrc =
                qpx + ((size_t)bh * NTOK + 1 + pos1) * XD + kc * 32 + lkg * 8;
            bf16x8 af = *reinterpret_cast<const bf16x8*>(qsrc);
            acc[m][0] = __builtin_amdgcn_mfma_f32_16x16x32_bf16(af, bfrag[0], acc[m][0], 0, 0, 0);
            acc[m][1] = __builtin_amdgcn_mfma_f32_16x16x32_bf16(af, bfrag[1], acc[m][1], 0, 0, 0);
        }
    }

    #pragma unroll
    for (int m = 0; m < 4; ++m) {
        #pragma unroll
        for (int r = 0; r < 4; ++r) {
            int rho = m0 + wave * 64 + m * 16 + lkg * 4 + r;
            if (rho >= RELROWS) continue;
            int bh = rho / 56, rem = rho % 56;
            int pos1 = (mode == 0) ? X * 56 + rem : rem * 56 + X;
            unsigned short* dst =
                qpx_out + ((size_t)bh * NTOK + 1 + pos1) * XD + 64 + mode * 28;
            dst[lm] = f2bf(acc[m][0][r] * 8.f);             // un-scale
            if (lm < 12) dst[16 + lm] = f2bf(acc[m][1][r] * 8.f);
        }
    }
}

// ---------------------------------------------------------------------------
// MFMA flash attention, bias folded into extended K-dim (128), 2-phase
// prefetch double-buffer, XCD-aware block swizzle.
// ---------------------------------------------------------------------------
__global__ __launch_bounds__(256) void attn_mfma(
    const unsigned short* __restrict__ qpx, const unsigned short* __restrict__ kpx,
    const unsigned short* __restrict__ vt, unsigned short* __restrict__ outp)
{
    __shared__ __align__(16) char kbuf[2][8192];   // Kext tile [32][128] bf16
    __shared__ __align__(16) char vbuf[2][4096];   // Vt tile  [64][32]  bf16
    __shared__ __align__(16) char pbuf[4][1024];   // per-wave P [16][32] bf16

    int bid0 = blockIdx.x;
    int bid = (bid0 & 7) * ((NBH * NQT) / 8) + (bid0 >> 3);   // XCD swizzle (2400%8==0)
    int tile = bid % NQT;
    int bh = bid / NQT;
    int head = bh % NHEAD, b = bh / NHEAD;
    int q0 = tile * QTILE;
    int t = threadIdx.x;
    int wave = t >> 6, lane = t & 63;
    int lm = lane & 15, lkg = lane >> 4;

    const unsigned short* kb  = kpx + (size_t)bh * NKEYPAD * XD;
    const unsigned short* vtb = vt + (size_t)bh * HD * NKEYPAD;

    // Q fragments: 4 chunks of 32 k-dims
    bf16x8 qf[4] = {};
    int qrow = q0 + wave * 16 + lm;
    if (qrow < NTOK) {
        const unsigned short* qs = qpx + ((size_t)bh * NTOK + qrow) * XD + lkg * 8;
        qf[0] = *reinterpret_cast<const bf16x8*>(qs);
        qf[1] = *reinterpret_cast<const bf16x8*>(qs + 32);
        qf[2] = *reinterpret_cast<const bf16x8*>(qs + 64);
        qf[3] = *reinterpret_cast<const bf16x8*>(qs + 96);
    }

    f32x4 oacc[4] = {};
    float osum[4] = {0.f, 0.f, 0.f, 0.f};

    // staging roles (pre-swizzled sources, linear LDS dest)
    int kr0 = t >> 4;
    int ks0 = (t & 15) ^ (kr0 & 7);
    int kr1 = kr0 + 16;
    const unsigned short* kp0 = kb + (size_t)kr0 * XD + ks0 * 8;
    const unsigned short* kp1 = kb + (size_t)kr1 * XD + ks0 * 8;
    int vr = t >> 2;
    int vs = (t & 3) ^ ((vr >> 1) & 3);
    const unsigned short* vp0 = vtb + (size_t)vr * NKEYPAD + vs * 8;
    int kd0 = wave * 1024, kd1 = 4096 + wave * 1024, vd = wave * 1024;

    const int NT = NKEYPAD / 32;   // 25

    // prologue: stage tile 0 into buffer 0
    gl16(kp0, &kbuf[0][kd0]); gl16(kp1, &kbuf[0][kd1]); gl16(vp0, &vbuf[0][vd]);
    kp0 += 32 * XD; kp1 += 32 * XD; vp0 += 32;
    __syncthreads();

    for (int jt = 0; jt < NT; ++jt) {
        int cur = jt & 1;
        if (jt + 1 < NT) {
            gl16(kp0, &kbuf[cur ^ 1][kd0]);
            gl16(kp1, &kbuf[cur ^ 1][kd1]);
            gl16(vp0, &vbuf[cur ^ 1][vd]);
            kp0 += 32 * XD; kp1 += 32 * XD; vp0 += 32;
        }

        // QK^T over 128 ext dims: S[16 q x 32 k] per wave
        f32x4 acc0 = {0.f, 0.f, 0.f, 0.f}, acc1 = {0.f, 0.f, 0.f, 0.f};
        #pragma unroll
        for (int kc = 0; kc < 4; ++kc) {
            int sl = (kc * 4 + lkg) ^ (lm & 7);
            bf16x8 kf0 = *reinterpret_cast<const bf16x8*>(&kbuf[cur][lm * 256 + sl * 16]);
            acc0 = __builtin_amdgcn_mfma_f32_16x16x32_bf16(qf[kc], kf0, acc0, 0, 0, 0);
            bf16x8 kf1 = *reinterpret_cast<const bf16x8*>(&kbuf[cur][(16 + lm) * 256 + sl * 16]);
            acc1 = __builtin_amdgcn_mfma_f32_16x16x32_bf16(qf[kc], kf1, acc1, 0, 0, 0);
        }

        // epilogue: exp only (scores complete, pads self-suppressed)
        #pragma unroll
        for (int nb = 0; nb < 2; ++nb) {
            f32x4 a = nb ? acc1 : acc0;
            #pragma unroll
            for (int r = 0; r < 4; ++r) {
                float e = __expf(a[r]);
                osum[r] += e;
                int baddr = (lkg * 4 + r) * 64 + (nb * 16 + lm) * 2;
                *reinterpret_cast<unsigned short*>(&pbuf[wave][swz64(baddr)]) = f2bf(e);
            }
        }

        // PV: O += P[16x32] * Vt
        bf16x8 pf = *reinterpret_cast<const bf16x8*>(&pbuf[wave][swz64(lm * 64 + lkg * 16)]);
        #pragma unroll
        for (int db = 0; db < 4; ++db) {
            int row = db * 16 + lm;
            bf16x8 vf = *reinterpret_cast<const bf16x8*>(
                &vbuf[cur][row * 64 + ((lkg ^ ((row >> 1) & 3)) << 4)]);
            oacc[db] = __builtin_amdgcn_mfma_f32_16x16x32_bf16(pf, vf, oacc[db], 0, 0, 0);
        }

        if (jt + 1 < NT) __syncthreads();
    }

    #pragma unroll
    for (int r = 0; r < 4; ++r) {
        float s = osum[r];
        s += __shfl_xor(s, 1, 64);
        s += __shfl_xor(s, 2, 64);
        s += __shfl_xor(s, 4, 64);
        s += __shfl_xor(s, 8, 64);
        osum[r] = 1.f / s;
    }
    #pragma unroll
    for (int r = 0; r < 4; ++r) {
        int qpos = q0 + wave * 16 + lkg * 4 + r;
        if (qpos >= NTOK) continue;
        unsigned short* orow = outp + ((size_t)b * NTOK + qpos) * DIM + (size_t)head * HD;
        const unsigned short* qres = qpx + ((size_t)bh * NTOK + qpos) * XD;
        #pragma unroll
        for (int db = 0; db < 4; ++db) {
            int d = db * 16 + lm;
            float o = oacc[db][r] * osum[r];
            if (qpos > 0) o += bf2f(qres[d]) * 8.f;   // residual (q was x0.125)
            orow[d] = f2bf(o);
        }
    }
}

// ---------------------------------------------------------------------------
extern "C" void kernel_launch(void* const* d_in, const int* in_sizes, int n_in,
                              void* d_out, int out_size, void* d_ws, size_t ws_size,
                              hipStream_t stream) {
    const float* x     = (const float*)d_in[0];
    const float* Wqkv  = (const float*)d_in[1];
    const float* pqw   = (const float*)d_in[2];
    const float* pkw   = (const float*)d_in[3];
    const float* pvw   = (const float*)d_in[4];
    const float* gq    = (const float*)d_in[5];
    const float* bq    = (const float*)d_in[6];
    const float* gk    = (const float*)d_in[7];
    const float* bk    = (const float*)d_in[8];
    const float* gv    = (const float*)d_in[9];
    const float* bv    = (const float*)d_in[10];
    const float* rph   = (const float*)d_in[11];
    const float* rpw   = (const float*)d_in[12];
    const float* Wproj = (const float*)d_in[13];
    const float* bproj = (const float*)d_in[14];

    unsigned short* qkvb  = (unsigned short*)d_ws;                 // [M][2304] bf16
    unsigned short* qpx   = qkvb + (size_t)MROWS * THREE_DIM;      // [48][3137][128]
    unsigned short* kpx   = qpx + (size_t)NBH * NTOK * XD;         // [48][800][128]
    unsigned short* vt16  = kpx + (size_t)NBH * NKEYPAD * XD;      // [48][64][800]
    unsigned short* xbf   = vt16 + (size_t)NBH * HD * NKEYPAD;     // [M][768]
    unsigned short* wqkvt = xbf + (size_t)MROWS * DIM;             // [2304][768]
    unsigned short* wprojt= wqkvt + (size_t)DIM * THREE_DIM;       // [768][768]
    unsigned short* rphb  = wprojt + (size_t)DIM * DIM;            // [111][64]
    unsigned short* rpwb  = rphb + 7104;
    unsigned short* attn_bf = qkvb;            // alias (qkvb dead after pools)

    dim3 blk(256);

    // 0) bf16 conversions
    cvt_bf16<<<2048, blk, 0, stream>>>(x, xbf, (int)((size_t)MROWS * DIM / 4));
    {
        dim3 g(THREE_DIM / 32, DIM / 32);
        transpose_bf16<<<g, blk, 0, stream>>>(Wqkv, wqkvt, DIM, THREE_DIM);
    }
    {
        dim3 g(DIM / 32, DIM / 32);
        transpose_bf16<<<g, blk, 0, stream>>>(Wproj, wprojt, DIM, DIM);
    }
    cvt_bf16<<<7, blk, 0, stream>>>(rph, rphb, 1776);
    cvt_bf16<<<7, blk, 0, stream>>>(rpw, rpwb, 1776);

    // 1) qkv = x @ Wqkv   (bf16 MFMA, bf16 out)
    {
        dim3 grid(THREE_DIM / 128, (MROWS + 127) / 128);
        gemm_mfma<<<grid, blk, 0, stream>>>(xbf, wqkvt, nullptr, qkvb,
                                            MROWS, THREE_DIM, DIM, 1);
    }

    // 2) pool + LN (row-tiled): q-ext, k-ext, v^T; then pad rows
    pool_ln_rows<<<NBH * QH, blk, 0, stream>>>(qkvb, pqw, gq, bq, qpx,  0, 1, QH, QW, 3);
    pool_ln_rows<<<NBH * 28, blk, 0, stream>>>(qkvb, pkw, gk, bk, kpx,  1, 2, 28, 28, 1);
    pool_ln_rows<<<NBH * 28, blk, 0, stream>>>(qkvb, pvw, gv, bv, vt16, 2, 2, 28, 28, 2);
    pad_kv<<<NBH, 64, 0, stream>>>(kpx, vt16);

    // 3) rel-pos dots -> Q-ext columns (bf16, in-place into qpx)
    {
        dim3 g(56, (RELROWS + 255) / 256);
        rel_mfma<<<g, blk, 0, stream>>>(qpx, rphb, qpx, 0);
        rel_mfma<<<g, blk, 0, stream>>>(qpx, rpwb, qpx, 1);
    }

    // 4) MFMA flash attention (bias folded) -> bf16
    attn_mfma<<<NBH * NQT, blk, 0, stream>>>(qpx, kpx, vt16, attn_bf);

    // 5) out = attn_out @ Wproj + bproj   (bf16 MFMA, fp32 out)
    {
        dim3 grid(DIM / 128, (MROWS + 127) / 128);
        gemm_mfma<<<grid, blk, 0, stream>>>(attn_bf, wprojt, bproj, d_out,
                                            MROWS, DIM, DIM, 0);
    }
}

// Round 7
// 329.407 us; speedup vs baseline: 23.6838x; 1.0152x over previous
//
#include <hip/hip_runtime.h>
#include <hip/hip_bf16.h>

// Problem constants (fixed by setup_inputs)
#define BATCH 4
#define NTOK 3137        // 1 + 56*56
#define DIM 768
#define NHEAD 12
#define HD 64
#define QH 56
#define QW 56
#define NKEY 785         // 1 + 28*28
#define NKEYPAD 800      // padded key count (25 x 32)
#define THREE_DIM 2304
#define MROWS (BATCH*NTOK)   // 12548
#define QTILE 64
#define NQT 50               // ceil(3137/64)
#define NBH 48               // BATCH*NHEAD
#define RELROWS (NBH*56)     // 2688
#define XD 128               // extended head dim (64 q + 28 relh + 28 relw + pad flag)

typedef __attribute__((ext_vector_type(8))) short bf16x8;
typedef __attribute__((ext_vector_type(4))) float f32x4;

__device__ __forceinline__ unsigned short f2bf(float f) {
    union { float f; unsigned u; } v; v.f = f;
    unsigned r = v.u + 0x7FFFu + ((v.u >> 16) & 1u);   // RNE
    return (unsigned short)(r >> 16);
}
__device__ __forceinline__ float bf2f(unsigned short s) {
    union { unsigned u; float f; } v; v.u = (unsigned)s << 16; return v.f;
}
// XOR swizzle (bijective) used by the P round-trip buffer
__device__ __forceinline__ int swz64(int x) { return x ^ (((x >> 6) & 7) << 4); }

__device__ __forceinline__ void gl16(const void* g, void* l) {
    __builtin_amdgcn_global_load_lds(
        (const __attribute__((address_space(1))) unsigned int*)g,
        (__attribute__((address_space(3))) unsigned int*)l, 16, 0, 0);
}

// ---------------------------------------------------------------------------
// fp32 -> bf16 elementwise (vectorized x4)
// ---------------------------------------------------------------------------
__global__ __launch_bounds__(256) void cvt_bf16(
    const float* __restrict__ in, unsigned short* __restrict__ outp, int n4)
{
    for (int i = blockIdx.x * 256 + threadIdx.x; i < n4; i += gridDim.x * 256) {
        float4 v = reinterpret_cast<const float4*>(in)[i];
        union { unsigned short s[4]; uint2 u; } o;
        o.s[0] = f2bf(v.x); o.s[1] = f2bf(v.y);
        o.s[2] = f2bf(v.z); o.s[3] = f2bf(v.w);
        reinterpret_cast<uint2*>(outp)[i] = o.u;
    }
}

// Both rel tables in one launch (n4 = 1776 each)
__global__ __launch_bounds__(256) void cvt_rel(
    const float* __restrict__ h, const float* __restrict__ w,
    unsigned short* __restrict__ hb, unsigned short* __restrict__ wb)
{
    int i = blockIdx.x * 256 + threadIdx.x;
    const float* src; unsigned short* dst; int j;
    if (i < 1776)      { src = h; dst = hb; j = i; }
    else if (i < 3552) { src = w; dst = wb; j = i - 1776; }
    else return;
    float4 v = reinterpret_cast<const float4*>(src)[j];
    union { unsigned short s[4]; uint2 u; } o;
    o.s[0] = f2bf(v.x); o.s[1] = f2bf(v.y);
    o.s[2] = f2bf(v.z); o.s[3] = f2bf(v.w);
    reinterpret_cast<uint2*>(dst)[j] = o.u;
}

// ---------------------------------------------------------------------------
// W[K][N] fp32 -> Wt[N][K] bf16; z=0: Wqkv(768x2304), z=1: Wproj(768x768)
// ---------------------------------------------------------------------------
__global__ __launch_bounds__(256) void transpose_bf16_2(
    const float* __restrict__ W0, unsigned short* __restrict__ Wt0,
    const float* __restrict__ W1, unsigned short* __restrict__ Wt1)
{
    const float* W; unsigned short* Wt; int N;
    if (blockIdx.z == 0) { W = W0; Wt = Wt0; N = THREE_DIM; }
    else {
        if (blockIdx.x >= DIM / 32) return;
        W = W1; Wt = Wt1; N = DIM;
    }
    const int K = DIM;
    __shared__ float tile[32][33];
    int k0 = blockIdx.y * 32, n0 = blockIdx.x * 32;
    int t = threadIdx.x;
    int r = t >> 5, c = t & 31;
    #pragma unroll
    for (int p = 0; p < 4; ++p)
        tile[r + p * 8][c] = W[(size_t)(k0 + r + p * 8) * N + n0 + c];
    __syncthreads();
    #pragma unroll
    for (int p = 0; p < 4; ++p)
        Wt[(size_t)(n0 + r + p * 8) * K + k0 + c] = f2bf(tile[c][r + p * 8]);
}

// ---------------------------------------------------------------------------
// bf16 MFMA GEMM: C[M][N] = A[M][K]bf16 * Bt[N][K]bf16 (+bias).
// 128x128 tile, BK=32, 4 waves, 2-buffer pipeline with COUNTED vmcnt
// (raw s_barrier, loads stay in flight across barriers - T3/T4),
// bijective XCD-aware block swizzle. out_bf16 selects bf16/fp32 C.
// ---------------------------------------------------------------------------
__global__ __launch_bounds__(256) void gemm_mfma(
    const unsigned short* __restrict__ A, const unsigned short* __restrict__ Bt,
    const float* __restrict__ bias, void* __restrict__ C,
    int M, int N, int K, int out_bf16)
{
    __shared__ __align__(16) char lds[32768];   // buf0: A[0,8K) B[8K,16K); buf1: +16K
    int t = threadIdx.x;
    int wave = t >> 6, lane = t & 63;
    int lm = lane & 15, lkg = lane >> 4;
    int wr = wave >> 1, wc = wave & 1;

    // bijective XCD remap (m204)
    int gx = gridDim.x;
    int nwg = gx * gridDim.y;
    int lin = blockIdx.y * gx + blockIdx.x;
    int qq = nwg >> 3, rr = nwg & 7;
    int xcd = lin & 7, idx = lin >> 3;
    int newlin = (xcd < rr ? xcd * (qq + 1) : rr * (qq + 1) + (xcd - rr) * qq) + idx;
    int m0 = (newlin / gx) * 128, n0 = (newlin % gx) * 128;

    // staging roles: two 16B chunks per matrix per thread, pre-swizzled source
    int o0 = wave * 2048 + lane * 16;
    int o1 = o0 + 1024;
    int r0 = o0 >> 6, s0 = ((o0 >> 4) & 3) ^ ((r0 >> 1) & 3);
    int r1 = o1 >> 6, s1 = ((o1 >> 4) & 3) ^ ((r1 >> 1) & 3);
    int ar0 = m0 + r0; if (ar0 >= M) ar0 = M - 1;
    int ar1 = m0 + r1; if (ar1 >= M) ar1 = M - 1;

    const unsigned short* ap0 = A + (size_t)ar0 * K + s0 * 8;
    const unsigned short* ap1 = A + (size_t)ar1 * K + s1 * 8;
    const unsigned short* bp0 = Bt + (size_t)(n0 + r0) * K + s0 * 8;
    const unsigned short* bp1 = Bt + (size_t)(n0 + r1) * K + s1 * 8;

    int oa0 = o0, oa1 = o1, ob0 = 8192 + o0, ob1 = 8192 + o1;

    f32x4 acc[4][4] = {};
    const int nt = K >> 5;

    // prologue: stage tile 0 into buffer 0 (stays in flight)
    gl16(ap0, &lds[oa0]); gl16(ap1, &lds[oa1]);
    gl16(bp0, &lds[ob0]); gl16(bp1, &lds[ob1]);
    ap0 += 32; ap1 += 32; bp0 += 32; bp1 += 32;

    for (int tt = 0; tt < nt; ++tt) {
        int cb = (tt & 1) << 14;
        if (tt + 1 < nt) {
            int nb2 = cb ^ 16384;
            gl16(ap0, &lds[nb2 + oa0]); gl16(ap1, &lds[nb2 + oa1]);
            gl16(bp0, &lds[nb2 + ob0]); gl16(bp1, &lds[nb2 + ob1]);
            ap0 += 32; ap1 += 32; bp0 += 32; bp1 += 32;
            // wait for tile tt's 4 loads only; next tile's 4 stay in flight
            asm volatile("s_waitcnt vmcnt(4)" ::: "memory");
        } else {
            asm volatile("s_waitcnt vmcnt(0)" ::: "memory");
        }
        __builtin_amdgcn_s_barrier();   // all waves' tile-tt loads landed

        bf16x8 af[4], bfr[4];
        #pragma unroll
        for (int m = 0; m < 4; ++m) {
            int row = wr * 64 + m * 16 + lm;
            af[m] = *reinterpret_cast<const bf16x8*>(
                &lds[cb + row * 64 + ((lkg ^ ((row >> 1) & 3)) << 4)]);
        }
        #pragma unroll
        for (int n = 0; n < 4; ++n) {
            int row = wc * 64 + n * 16 + lm;
            bfr[n] = *reinterpret_cast<const bf16x8*>(
                &lds[cb + 8192 + row * 64 + ((lkg ^ ((row >> 1) & 3)) << 4)]);
        }
        #pragma unroll
        for (int m = 0; m < 4; ++m)
            #pragma unroll
            for (int n = 0; n < 4; ++n)
                acc[m][n] = __builtin_amdgcn_mfma_f32_16x16x32_bf16(
                    af[m], bfr[n], acc[m][n], 0, 0, 0);
        // all waves' ds_reads of buf cb retired by barrier arrival
        // (compiler waits lgkmcnt before the MFMAs that consume them)
        __builtin_amdgcn_s_barrier();
    }

    #pragma unroll
    for (int n = 0; n < 4; ++n) {
        int col = n0 + wc * 64 + n * 16 + lm;
        float bval = bias ? bias[col] : 0.f;
        #pragma unroll
        for (int m = 0; m < 4; ++m) {
            int row = m0 + wr * 64 + m * 16 + lkg * 4;
            #pragma unroll
            for (int r = 0; r < 4; ++r) {
                if (row + r < M) {
                    float o = acc[m][n][r] + bval;
                    if (out_bf16)
                        ((unsigned short*)C)[(size_t)(row + r) * N + col] = f2bf(o);
                    else
                        ((float*)C)[(size_t)(row + r) * N + col] = o;
                }
            }
        }
    }
}

// ---------------------------------------------------------------------------
// Row-tiled depthwise 3x3 pool + LayerNorm. One block per (bh, out-row).
// mode 3: q-ext [bh][pos][128]; mode 1: k-ext [bh][pos][128]; mode 2: v^T
// ---------------------------------------------------------------------------
__global__ __launch_bounds__(256) void pool_ln_rows(
    const unsigned short* __restrict__ qkvb, const float* __restrict__ w,
    const float* __restrict__ g, const float* __restrict__ beta,
    unsigned short* __restrict__ outp, int qi, int stride, int OH, int OW,
    int mode)
{
    __shared__ unsigned short ibuf[3 * 56 * 64];   // 21.5 KB
    int bid = blockIdx.x;
    int orow = bid % OH;
    int bh = bid / OH;
    int head = bh % NHEAD, b = bh / NHEAD;
    int t = threadIdx.x;
    int wave = t >> 6, lane = t & 63;

    const unsigned short* src =
        qkvb + (size_t)b * NTOK * THREE_DIM + (size_t)qi * DIM + (size_t)head * HD;

    for (int i = t; i < 3 * 56 * 32; i += 256) {
        int pair = i >> 5, off = i & 31;
        int r = pair / 56, iw = pair % 56;
        int ih = orow * stride + r - 1;
        unsigned v = 0;
        if (ih >= 0 && ih < QH)
            v = *reinterpret_cast<const unsigned*>(
                src + (size_t)(1 + ih * QW + iw) * THREE_DIM + off * 2);
        *reinterpret_cast<unsigned*>(&ibuf[pair * 64 + off * 2]) = v;
    }

    float wreg[9];
    #pragma unroll
    for (int k = 0; k < 9; ++k) wreg[k] = w[lane * 9 + k];
    float gl = g[lane], bl = beta[lane];
    __syncthreads();

    int ntask = OW + ((orow == 0) ? 1 : 0);    // extra task: cls (pos 0)
    for (int task = wave; task < ntask; task += 4) {
        float val;
        int pos;
        if (task == OW) {                      // cls token
            val = bf2f(src[lane]);
            pos = 0;
        } else {
            int ow = task;
            float acc = 0.f;
            #pragma unroll
            for (int r = 0; r < 3; ++r) {
                #pragma unroll
                for (int c = 0; c < 3; ++c) {
                    int iwc = ow * stride + c - 1;
                    if (iwc < 0 || iwc >= QW) continue;
                    acc += bf2f(ibuf[(r * 56 + iwc) * 64 + lane]) * wreg[r * 3 + c];
                }
            }
            val = acc;
            pos = 1 + orow * OW + ow;
        }

        float mu = val;
        #pragma unroll
        for (int off = 32; off > 0; off >>= 1) mu += __shfl_xor(mu, off, 64);
        mu *= (1.f / 64.f);
        float dv = val - mu;
        float var = dv * dv;
        #pragma unroll
        for (int off = 32; off > 0; off >>= 1) var += __shfl_xor(var, off, 64);
        var *= (1.f / 64.f);
        float o = dv * rsqrtf(var + 1e-5f) * gl + bl;

        if (mode == 3) {
            unsigned short* row = outp + ((size_t)bh * NTOK + pos) * XD;
            row[lane] = f2bf(o * 0.125f);
            row[64 + lane] = (lane == 56) ? f2bf(-30.f) : 0;
        } else if (mode == 1) {
            unsigned short* row = outp + ((size_t)bh * NKEYPAD + pos) * XD;
            row[lane] = f2bf(o);
            unsigned short ext = 0;
            if (pos > 0) {
                int kh = (pos - 1) / 28, kw = (pos - 1) % 28;
                if ((lane < 28 && lane == kh) ||
                    (lane >= 28 && lane < 56 && lane - 28 == kw))
                    ext = 0x3F80;   // 1.0 bf16
            }
            row[64 + lane] = ext;
        } else {
            outp[((size_t)bh * HD + lane) * NKEYPAD + pos] = f2bf(o);
        }
    }
}

// ---------------------------------------------------------------------------
// Pad rows (785..799): k-ext rows = pad-flag onehot; v^T pad cols = 0.
// ---------------------------------------------------------------------------
__global__ __launch_bounds__(64) void pad_kv(
    unsigned short* __restrict__ kpx, unsigned short* __restrict__ vt16)
{
    int bh = blockIdx.x;
    int t = threadIdx.x;
    for (int pos = NKEY; pos < NKEYPAD; ++pos) {
        unsigned short* row = kpx + ((size_t)bh * NKEYPAD + pos) * XD;
        row[t] = 0;
        row[64 + t] = (t == 56) ? 0x3F80 : 0;
        vt16[((size_t)bh * HD + t) * NKEYPAD + pos] = 0;
    }
}

// ---------------------------------------------------------------------------
// MFMA rel-pos dots -> bf16 Q-ext columns of qpx.
// mode 0 (rel_h): rows=(bh,w) at fixed h=X, cols 64..91
// mode 1 (rel_w): rows=(bh,h) at fixed w=X, cols 92..119
// ---------------------------------------------------------------------------
__global__ __launch_bounds__(256) void rel_mfma(
    const unsigned short* __restrict__ qpx, const unsigned short* __restrict__ rtab,
    unsigned short* __restrict__ qpx_out, int mode)
{
    __shared__ char bbuf[4096];     // [32 rows][64 bf16], XOR-swizzled
    int X = blockIdx.x;
    int m0 = blockIdx.y * 256;
    int t = threadIdx.x;
    int wave = t >> 6, lane = t & 63;
    int lm = lane & 15, lkg = lane >> 4;

    {
        int row = t >> 3, c8 = t & 7;
        int4 val = {0, 0, 0, 0};
        if (row < 28) {
            int dh = X - 2 * row + 54;              // in [0, 110)
            val = *reinterpret_cast<const int4*>(rtab + (size_t)dh * HD + c8 * 8);
        }
        *reinterpret_cast<int4*>(&bbuf[row * 128 + ((c8 * 16) ^ ((row & 7) << 4))]) = val;
    }
    __syncthreads();

    int rbase = m0 + wave * 64 + lm;
    f32x4 acc[4][2] = {};
    #pragma unroll
    for (int kc = 0; kc < 2; ++kc) {
        bf16x8 bfrag[2];
        #pragma unroll
        for (int nb = 0; nb < 2; ++nb) {
            int row = nb * 16 + lm;
            bfrag[nb] = *reinterpret_cast<const bf16x8*>(
                &bbuf[row * 128 + (((kc * 4 + lkg) * 16) ^ ((row & 7) << 4))]);
        }
        #pragma unroll
        for (int m = 0; m < 4; ++m) {
            int rho = rbase + m * 16; if (rho > RELROWS - 1) rho = RELROWS - 1;
            int bh = rho / 56, rem = rho % 56;
            int pos1 = (mode == 0) ? X * 56 + rem : rem * 56 + X;
            const unsigned short* qsrc =
                qpx + ((size_t)bh * NTOK + 1 + pos1) * XD + kc * 32 + lkg * 8;
            bf16x8 af = *reinterpret_cast<const bf16x8*>(qsrc);
            acc[m][0] = __builtin_amdgcn_mfma_f32_16x16x32_bf16(af, bfrag[0], acc[m][0], 0, 0, 0);
            acc[m][1] = __builtin_amdgcn_mfma_f32_16x16x32_bf16(af, bfrag[1], acc[m][1], 0, 0, 0);
        }
    }

    #pragma unroll
    for (int m = 0; m < 4; ++m) {
        #pragma unroll
        for (int r = 0; r < 4; ++r) {
            int rho = m0 + wave * 64 + m * 16 + lkg * 4 + r;
            if (rho >= RELROWS) continue;
            int bh = rho / 56, rem = rho % 56;
            int pos1 = (mode == 0) ? X * 56 + rem : rem * 56 + X;
            unsigned short* dst =
                qpx_out + ((size_t)bh * NTOK + 1 + pos1) * XD + 64 + mode * 28;
            dst[lm] = f2bf(acc[m][0][r] * 8.f);             // un-scale
            if (lm < 12) dst[16 + lm] = f2bf(acc[m][1][r] * 8.f);
        }
    }
}

// ---------------------------------------------------------------------------
// MFMA flash attention, bias folded into extended K-dim (128), counted-vmcnt
// double-buffer pipeline (raw barriers), XCD-aware block swizzle.
// ---------------------------------------------------------------------------
__global__ __launch_bounds__(256) void attn_mfma(
    const unsigned short* __restrict__ qpx, const unsigned short* __restrict__ kpx,
    const unsigned short* __restrict__ vt, unsigned short* __restrict__ outp)
{
    __shared__ __align__(16) char kbuf[2][8192];   // Kext tile [32][128] bf16
    __shared__ __align__(16) char vbuf[2][4096];   // Vt tile  [64][32]  bf16
    __shared__ __align__(16) char pbuf[4][1024];   // per-wave P [16][32] bf16

    int bid0 = blockIdx.x;
    int bid = (bid0 & 7) * ((NBH * NQT) / 8) + (bid0 >> 3);   // XCD swizzle
    int tile = bid % NQT;
    int bh = bid / NQT;
    int head = bh % NHEAD, b = bh / NHEAD;
    int q0 = tile * QTILE;
    int t = threadIdx.x;
    int wave = t >> 6, lane = t & 63;
    int lm = lane & 15, lkg = lane >> 4;

    const unsigned short* kb  = kpx + (size_t)bh * NKEYPAD * XD;
    const unsigned short* vtb = vt + (size_t)bh * HD * NKEYPAD;

    bf16x8 qf[4] = {};
    int qrow = q0 + wave * 16 + lm;
    if (qrow < NTOK) {
        const unsigned short* qs = qpx + ((size_t)bh * NTOK + qrow) * XD + lkg * 8;
        qf[0] = *reinterpret_cast<const bf16x8*>(qs);
        qf[1] = *reinterpret_cast<const bf16x8*>(qs + 32);
        qf[2] = *reinterpret_cast<const bf16x8*>(qs + 64);
        qf[3] = *reinterpret_cast<const bf16x8*>(qs + 96);
    }

    f32x4 oacc[4] = {};
    float osum[4] = {0.f, 0.f, 0.f, 0.f};

    int kr0 = t >> 4;
    int ks0 = (t & 15) ^ (kr0 & 7);
    int kr1 = kr0 + 16;
    const unsigned short* kp0 = kb + (size_t)kr0 * XD + ks0 * 8;
    const unsigned short* kp1 = kb + (size_t)kr1 * XD + ks0 * 8;
    int vr = t >> 2;
    int vs = (t & 3) ^ ((vr >> 1) & 3);
    const unsigned short* vp0 = vtb + (size_t)vr * NKEYPAD + vs * 8;
    int kd0 = wave * 1024, kd1 = 4096 + wave * 1024, vd = wave * 1024;

    const int NT = NKEYPAD / 32;   // 25

    // prologue: stage tile 0 into buffer 0 (stays in flight)
    gl16(kp0, &kbuf[0][kd0]); gl16(kp1, &kbuf[0][kd1]); gl16(vp0, &vbuf[0][vd]);
    kp0 += 32 * XD; kp1 += 32 * XD; vp0 += 32;

    for (int jt = 0; jt < NT; ++jt) {
        int cur = jt & 1;
        if (jt + 1 < NT) {
            gl16(kp0, &kbuf[cur ^ 1][kd0]);
            gl16(kp1, &kbuf[cur ^ 1][kd1]);
            gl16(vp0, &vbuf[cur ^ 1][vd]);
            kp0 += 32 * XD; kp1 += 32 * XD; vp0 += 32;
            asm volatile("s_waitcnt vmcnt(3)" ::: "memory");
        } else {
            asm volatile("s_waitcnt vmcnt(0)" ::: "memory");
        }
        __builtin_amdgcn_s_barrier();   // all waves' tile-jt loads landed

        // QK^T over 128 ext dims: S[16 q x 32 k] per wave
        f32x4 acc0 = {0.f, 0.f, 0.f, 0.f}, acc1 = {0.f, 0.f, 0.f, 0.f};
        #pragma unroll
        for (int kc = 0; kc < 4; ++kc) {
            int sl = (kc * 4 + lkg) ^ (lm & 7);
            bf16x8 kf0 = *reinterpret_cast<const bf16x8*>(&kbuf[cur][lm * 256 + sl * 16]);
            acc0 = __builtin_amdgcn_mfma_f32_16x16x32_bf16(qf[kc], kf0, acc0, 0, 0, 0);
            bf16x8 kf1 = *reinterpret_cast<const bf16x8*>(&kbuf[cur][(16 + lm) * 256 + sl * 16]);
            acc1 = __builtin_amdgcn_mfma_f32_16x16x32_bf16(qf[kc], kf1, acc1, 0, 0, 0);
        }

        // epilogue: exp only (scores complete, pads self-suppressed)
        #pragma unroll
        for (int nb = 0; nb < 2; ++nb) {
            f32x4 a = nb ? acc1 : acc0;
            #pragma unroll
            for (int r = 0; r < 4; ++r) {
                float e = __expf(a[r]);
                osum[r] += e;
                int baddr = (lkg * 4 + r) * 64 + (nb * 16 + lm) * 2;
                *reinterpret_cast<unsigned short*>(&pbuf[wave][swz64(baddr)]) = f2bf(e);
            }
        }

        // PV: O += P[16x32] * Vt
        bf16x8 pf = *reinterpret_cast<const bf16x8*>(&pbuf[wave][swz64(lm * 64 + lkg * 16)]);
        #pragma unroll
        for (int db = 0; db < 4; ++db) {
            int row = db * 16 + lm;
            bf16x8 vf = *reinterpret_cast<const bf16x8*>(
                &vbuf[cur][row * 64 + ((lkg ^ ((row >> 1) & 3)) << 4)]);
            oacc[db] = __builtin_amdgcn_mfma_f32_16x16x32_bf16(pf, vf, oacc[db], 0, 0, 0);
        }

        __builtin_amdgcn_s_barrier();   // all reads of buf[cur] retired
    }

    #pragma unroll
    for (int r = 0; r < 4; ++r) {
        float s = osum[r];
        s += __shfl_xor(s, 1, 64);
        s += __shfl_xor(s, 2, 64);
        s += __shfl_xor(s, 4, 64);
        s += __shfl_xor(s, 8, 64);
        osum[r] = 1.f / s;
    }
    #pragma unroll
    for (int r = 0; r < 4; ++r) {
        int qpos = q0 + wave * 16 + lkg * 4 + r;
        if (qpos >= NTOK) continue;
        unsigned short* orow = outp + ((size_t)b * NTOK + qpos) * DIM + (size_t)head * HD;
        const unsigned short* qres = qpx + ((size_t)bh * NTOK + qpos) * XD;
        #pragma unroll
        for (int db = 0; db < 4; ++db) {
            int d = db * 16 + lm;
            float o = oacc[db][r] * osum[r];
            if (qpos > 0) o += bf2f(qres[d]) * 8.f;   // residual (q was x0.125)
            orow[d] = f2bf(o);
        }
    }
}

// ---------------------------------------------------------------------------
extern "C" void kernel_launch(void* const* d_in, const int* in_sizes, int n_in,
                              void* d_out, int out_size, void* d_ws, size_t ws_size,
                              hipStream_t stream) {
    const float* x     = (const float*)d_in[0];
    const float* Wqkv  = (const float*)d_in[1];
    const float* pqw   = (const float*)d_in[2];
    const float* pkw   = (const float*)d_in[3];
    const float* pvw   = (const float*)d_in[4];
    const float* gq    = (const float*)d_in[5];
    const float* bq    = (const float*)d_in[6];
    const float* gk    = (const float*)d_in[7];
    const float* bk    = (const float*)d_in[8];
    const float* gv    = (const float*)d_in[9];
    const float* bv    = (const float*)d_in[10];
    const float* rph   = (const float*)d_in[11];
    const float* rpw   = (const float*)d_in[12];
    const float* Wproj = (const float*)d_in[13];
    const float* bproj = (const float*)d_in[14];

    unsigned short* qkvb  = (unsigned short*)d_ws;                 // [M][2304] bf16
    unsigned short* qpx   = qkvb + (size_t)MROWS * THREE_DIM;      // [48][3137][128]
    unsigned short* kpx   = qpx + (size_t)NBH * NTOK * XD;         // [48][800][128]
    unsigned short* vt16  = kpx + (size_t)NBH * NKEYPAD * XD;      // [48][64][800]
    unsigned short* xbf   = vt16 + (size_t)NBH * HD * NKEYPAD;     // [M][768]
    unsigned short* wqkvt = xbf + (size_t)MROWS * DIM;             // [2304][768]
    unsigned short* wprojt= wqkvt + (size_t)DIM * THREE_DIM;       // [768][768]
    unsigned short* rphb  = wprojt + (size_t)DIM * DIM;            // [111][64]
    unsigned short* rpwb  = rphb + 7104;
    unsigned short* attn_bf = qkvb;            // alias (qkvb dead after pools)

    dim3 blk(256);

    // 0) bf16 conversions (consolidated)
    cvt_bf16<<<2048, blk, 0, stream>>>(x, xbf, (int)((size_t)MROWS * DIM / 4));
    {
        dim3 g(THREE_DIM / 32, DIM / 32, 2);
        transpose_bf16_2<<<g, blk, 0, stream>>>(Wqkv, wqkvt, Wproj, wprojt);
    }
    cvt_rel<<<14, blk, 0, stream>>>(rph, rpw, rphb, rpwb);

    // 1) qkv = x @ Wqkv   (bf16 MFMA, bf16 out)
    {
        dim3 grid(THREE_DIM / 128, (MROWS + 127) / 128);
        gemm_mfma<<<grid, blk, 0, stream>>>(xbf, wqkvt, nullptr, qkvb,
                                            MROWS, THREE_DIM, DIM, 1);
    }

    // 2) pool + LN (row-tiled): q-ext, k-ext, v^T; then pad rows
    pool_ln_rows<<<NBH * QH, blk, 0, stream>>>(qkvb, pqw, gq, bq, qpx,  0, 1, QH, QW, 3);
    pool_ln_rows<<<NBH * 28, blk, 0, stream>>>(qkvb, pkw, gk, bk, kpx,  1, 2, 28, 28, 1);
    pool_ln_rows<<<NBH * 28, blk, 0, stream>>>(qkvb, pvw, gv, bv, vt16, 2, 2, 28, 28, 2);
    pad_kv<<<NBH, 64, 0, stream>>>(kpx, vt16);

    // 3) rel-pos dots -> Q-ext columns (bf16, in-place into qpx)
    {
        dim3 g(56, (RELROWS + 255) / 256);
        rel_mfma<<<g, blk, 0, stream>>>(qpx, rphb, qpx, 0);
        rel_mfma<<<g, blk, 0, stream>>>(qpx, rpwb, qpx, 1);
    }

    // 4) MFMA flash attention (bias folded) -> bf16
    attn_mfma<<<NBH * NQT, blk, 0, stream>>>(qpx, kpx, vt16, attn_bf);

    // 5) out = attn_out @ Wproj + bproj   (bf16 MFMA, fp32 out)
    {
        dim3 grid(DIM / 128, (MROWS + 127) / 128);
        gemm_mfma<<<grid, blk, 0, stream>>>(attn_bf, wprojt, bproj, d_out,
                                            MROWS, DIM, DIM, 0);
    }
}